// Round 1
// baseline (920.602 us; speedup 1.0000x reference)
//
#include <hip/hip_runtime.h>
#include <math.h>

// ---------------------------------------------------------------------------
// Graph net: per layer  (gather -> sum/max agg -> 2-way attention -> MLP ->
// BN affine -> GRUCell), then final MLP.  fp32 baseline.
// ---------------------------------------------------------------------------

__device__ __forceinline__ float4 ld4(const float* __restrict__ p) {
    return *(const float4*)p;
}

// ---------------- CSR build ----------------
__global__ void k_deg(const int* __restrict__ ei, int* __restrict__ cnt, int E) {
    int e = blockIdx.x * 256 + threadIdx.x;
    if (e < E) {
        atomicAdd(&cnt[ei[e]], 1);       // src gets neighbor dst
        atomicAdd(&cnt[ei[E + e]], 1);   // dst gets neighbor src
    }
}

__global__ __launch_bounds__(1024) void k_scan(const int* __restrict__ cnt,
                                               int* __restrict__ offs, int N) {
    __shared__ int sd[1024];
    int t = threadIdx.x;
    int carry = 0;
    if (t == 0) offs[0] = 0;
    for (int base = 0; base < N; base += 1024) {
        int v = (base + t < N) ? cnt[base + t] : 0;
        sd[t] = v;
        __syncthreads();
        for (int o = 1; o < 1024; o <<= 1) {
            int u = (t >= o) ? sd[t - o] : 0;
            __syncthreads();
            sd[t] += u;
            __syncthreads();
        }
        if (base + t < N) offs[base + t + 1] = carry + sd[t];
        carry += sd[1023];
        __syncthreads();
    }
}

__global__ void k_fill(const int* __restrict__ ei, int* __restrict__ cur,
                       int* __restrict__ adj, int E) {
    int e = blockIdx.x * 256 + threadIdx.x;
    if (e < E) {
        int s = ei[e], d = ei[E + e];
        int p = atomicAdd(&cur[s], 1); adj[p] = d;
        int q = atomicAdd(&cur[d], 1); adj[q] = s;
    }
}

// ---------------- aggregation + attention + comb (one wave per node) -------
__global__ __launch_bounds__(256) void k_agg(const float* __restrict__ x,
                                             const int* __restrict__ adj,
                                             const int* __restrict__ offs,
                                             const float* __restrict__ aW,  // [256][2]
                                             const float* __restrict__ ab,  // [2]
                                             float* __restrict__ comb, int N) {
    int n = blockIdx.x * 4 + (threadIdx.x >> 6);
    if (n >= N) return;
    int lane = threadIdx.x & 63;
    int f0 = 2 * lane;

    int beg = offs[n], end = offs[n + 1];
    float sx = 0.f, sy = 0.f;
    float mx = -3.402823e38f, my = -3.402823e38f;
    for (int j = beg; j < end; ++j) {
        int nb = adj[j];
        float2 v = *(const float2*)(x + (size_t)nb * 128 + f0);
        sx += v.x; sy += v.y;
        mx = fmaxf(mx, v.x); my = fmaxf(my, v.y);
    }
    if (beg == end) { mx = 0.f; my = 0.f; }  // isolated node: max -> 0

    // scores = [s_agg, m_agg] @ aW + ab    (aW row-major [256][2])
    float4 wS = ld4(aW + (size_t)f0 * 2);          // rows f0, f0+1, cols 0..1
    float4 wM = ld4(aW + (size_t)(128 + f0) * 2);
    float p0 = sx * wS.x + sy * wS.z + mx * wM.x + my * wM.z;
    float p1 = sx * wS.y + sy * wS.w + mx * wM.y + my * wM.w;
    for (int o = 32; o; o >>= 1) {
        p0 += __shfl_xor(p0, o);
        p1 += __shfl_xor(p1, o);
    }
    p0 += ab[0]; p1 += ab[1];
    float pm = fmaxf(p0, p1);
    float e0 = expf(p0 - pm), e1 = expf(p1 - pm);
    float w0 = e0 / (e0 + e1), w1 = 1.f - w0;

    float2 xv = *(const float2*)(x + (size_t)n * 128 + f0);
    float2 c;
    c.x = xv.x + w0 * sx + w1 * mx;
    c.y = xv.y + w0 * sy + w1 * my;
    *(float2*)(comb + (size_t)n * 128 + f0) = c;
}

// ---------------- tiled fp32 GEMM: C = act(A[M,128] @ W[128,Nc] + b) -------
// block tile 64x64, thread tile 4x4, K chunks of 64
template <int ACT, bool BN>
__global__ __launch_bounds__(256) void k_gemm(const float* __restrict__ A,
                                              const float* __restrict__ W,
                                              const float* __restrict__ bias,
                                              const float* __restrict__ gamma,
                                              const float* __restrict__ beta,
                                              float* __restrict__ C, int M, int Nc) {
    __shared__ float a_s[64][68];
    __shared__ float w_s[64][64];
    const int t = threadIdx.x, tx = t & 15, ty = t >> 4;
    const int m0 = blockIdx.x * 64, cb = blockIdx.y * 64;
    float acc[4][4] = {};

    for (int k0 = 0; k0 < 128; k0 += 64) {
#pragma unroll
        for (int i = 0; i < 4; ++i) {
            int f4 = t + i * 256;
            int row = f4 >> 4, q = f4 & 15;
            float4 v = make_float4(0.f, 0.f, 0.f, 0.f);
            if (m0 + row < M) v = ld4(A + (size_t)(m0 + row) * 128 + k0 + q * 4);
            *(float4*)&a_s[row][q * 4] = v;
            *(float4*)&w_s[row][q * 4] = ld4(W + (size_t)(k0 + row) * Nc + cb + q * 4);
        }
        __syncthreads();
#pragma unroll 16
        for (int kk = 0; kk < 64; ++kk) {
            float4 wv = *(float4*)&w_s[kk][tx * 4];
#pragma unroll
            for (int i = 0; i < 4; ++i) {
                float av = a_s[ty * 4 + i][kk];
                acc[i][0] += av * wv.x; acc[i][1] += av * wv.y;
                acc[i][2] += av * wv.z; acc[i][3] += av * wv.w;
            }
        }
        __syncthreads();
    }

    float4 bv = ld4(bias + cb + tx * 4);
    float4 gv = make_float4(1.f, 1.f, 1.f, 1.f), tv = make_float4(0.f, 0.f, 0.f, 0.f);
    if (BN) { gv = ld4(gamma + cb + tx * 4); tv = ld4(beta + cb + tx * 4); }
#pragma unroll
    for (int i = 0; i < 4; ++i) {
        int row = m0 + ty * 4 + i;
        if (row < M) {
            float4 o = make_float4(acc[i][0] + bv.x, acc[i][1] + bv.y,
                                   acc[i][2] + bv.z, acc[i][3] + bv.w);
            if (BN) {
                o.x = o.x * gv.x + tv.x; o.y = o.y * gv.y + tv.y;
                o.z = o.z * gv.z + tv.z; o.w = o.w * gv.w + tv.w;
            }
            if (ACT == 1) {
                o.x = fmaxf(o.x, 0.f); o.y = fmaxf(o.y, 0.f);
                o.z = fmaxf(o.z, 0.f); o.w = fmaxf(o.w, 0.f);
            }
            *(float4*)&C[(size_t)row * Nc + cb + tx * 4] = o;
        }
    }
}

// ---------------- GRU pass 1: r,u = sigmoid(z@Wih[:,c] + bih + h@Whh[:,c] + bhh)
// cols 0..255 of the gate matrices; RU layout [N][256] = [r | u]
__global__ __launch_bounds__(256) void k_gru_ru(const float* __restrict__ Z,
                                                const float* __restrict__ H,
                                                const float* __restrict__ Wih,
                                                const float* __restrict__ Whh,
                                                const float* __restrict__ bih,
                                                const float* __restrict__ bhh,
                                                float* __restrict__ RU, int M) {
    __shared__ float z_s[64][68], h_s[64][68];
    __shared__ float wi_s[64][64], wh_s[64][64];
    const int t = threadIdx.x, tx = t & 15, ty = t >> 4;
    const int m0 = blockIdx.x * 64, cg = blockIdx.y * 64;  // cg in {0,64,128,192}
    float ai[4][4] = {}, ah[4][4] = {};

    for (int k0 = 0; k0 < 128; k0 += 64) {
#pragma unroll
        for (int i = 0; i < 4; ++i) {
            int f4 = t + i * 256;
            int row = f4 >> 4, q = f4 & 15;
            float4 zv = make_float4(0.f, 0.f, 0.f, 0.f), hv = zv;
            if (m0 + row < M) {
                zv = ld4(Z + (size_t)(m0 + row) * 128 + k0 + q * 4);
                hv = ld4(H + (size_t)(m0 + row) * 128 + k0 + q * 4);
            }
            *(float4*)&z_s[row][q * 4] = zv;
            *(float4*)&h_s[row][q * 4] = hv;
            *(float4*)&wi_s[row][q * 4] = ld4(Wih + (size_t)(k0 + row) * 384 + cg + q * 4);
            *(float4*)&wh_s[row][q * 4] = ld4(Whh + (size_t)(k0 + row) * 384 + cg + q * 4);
        }
        __syncthreads();
#pragma unroll 8
        for (int kk = 0; kk < 64; ++kk) {
            float4 wi = *(float4*)&wi_s[kk][tx * 4];
            float4 wh = *(float4*)&wh_s[kk][tx * 4];
#pragma unroll
            for (int i = 0; i < 4; ++i) {
                float zv = z_s[ty * 4 + i][kk], hv = h_s[ty * 4 + i][kk];
                ai[i][0] += zv * wi.x; ai[i][1] += zv * wi.y;
                ai[i][2] += zv * wi.z; ai[i][3] += zv * wi.w;
                ah[i][0] += hv * wh.x; ah[i][1] += hv * wh.y;
                ah[i][2] += hv * wh.z; ah[i][3] += hv * wh.w;
            }
        }
        __syncthreads();
    }

    float4 bi = ld4(bih + cg + tx * 4), bh = ld4(bhh + cg + tx * 4);
#pragma unroll
    for (int i = 0; i < 4; ++i) {
        int row = m0 + ty * 4 + i;
        if (row < M) {
            float v0 = ai[i][0] + bi.x + ah[i][0] + bh.x;
            float v1 = ai[i][1] + bi.y + ah[i][1] + bh.y;
            float v2 = ai[i][2] + bi.z + ah[i][2] + bh.z;
            float v3 = ai[i][3] + bi.w + ah[i][3] + bh.w;
            float4 o = make_float4(1.f / (1.f + expf(-v0)), 1.f / (1.f + expf(-v1)),
                                   1.f / (1.f + expf(-v2)), 1.f / (1.f + expf(-v3)));
            *(float4*)&RU[(size_t)row * 256 + cg + tx * 4] = o;
        }
    }
}

// ---------------- GRU pass 2: n = tanh(in + r*hn); h' = (1-u)*n + u*h ------
// gate-n columns (256..383); writes new hidden state
__global__ __launch_bounds__(256) void k_gru_nc(const float* __restrict__ Z,
                                                const float* __restrict__ H,
                                                const float* __restrict__ Wih,
                                                const float* __restrict__ Whh,
                                                const float* __restrict__ bih,
                                                const float* __restrict__ bhh,
                                                const float* __restrict__ RU,
                                                float* __restrict__ Hn, int M) {
    __shared__ float z_s[64][68], h_s[64][68];
    __shared__ float wi_s[64][64], wh_s[64][64];
    const int t = threadIdx.x, tx = t & 15, ty = t >> 4;
    const int m0 = blockIdx.x * 64, cg = blockIdx.y * 64;  // cg in {0,64}
    float ai[4][4] = {}, ah[4][4] = {};

    for (int k0 = 0; k0 < 128; k0 += 64) {
#pragma unroll
        for (int i = 0; i < 4; ++i) {
            int f4 = t + i * 256;
            int row = f4 >> 4, q = f4 & 15;
            float4 zv = make_float4(0.f, 0.f, 0.f, 0.f), hv = zv;
            if (m0 + row < M) {
                zv = ld4(Z + (size_t)(m0 + row) * 128 + k0 + q * 4);
                hv = ld4(H + (size_t)(m0 + row) * 128 + k0 + q * 4);
            }
            *(float4*)&z_s[row][q * 4] = zv;
            *(float4*)&h_s[row][q * 4] = hv;
            *(float4*)&wi_s[row][q * 4] = ld4(Wih + (size_t)(k0 + row) * 384 + 256 + cg + q * 4);
            *(float4*)&wh_s[row][q * 4] = ld4(Whh + (size_t)(k0 + row) * 384 + 256 + cg + q * 4);
        }
        __syncthreads();
#pragma unroll 8
        for (int kk = 0; kk < 64; ++kk) {
            float4 wi = *(float4*)&wi_s[kk][tx * 4];
            float4 wh = *(float4*)&wh_s[kk][tx * 4];
#pragma unroll
            for (int i = 0; i < 4; ++i) {
                float zv = z_s[ty * 4 + i][kk], hv = h_s[ty * 4 + i][kk];
                ai[i][0] += zv * wi.x; ai[i][1] += zv * wi.y;
                ai[i][2] += zv * wi.z; ai[i][3] += zv * wi.w;
                ah[i][0] += hv * wh.x; ah[i][1] += hv * wh.y;
                ah[i][2] += hv * wh.z; ah[i][3] += hv * wh.w;
            }
        }
        __syncthreads();
    }

    float4 bi = ld4(bih + 256 + cg + tx * 4), bh = ld4(bhh + 256 + cg + tx * 4);
#pragma unroll
    for (int i = 0; i < 4; ++i) {
        int row = m0 + ty * 4 + i;
        if (row < M) {
            float4 rv = ld4(RU + (size_t)row * 256 + cg + tx * 4);
            float4 uv = ld4(RU + (size_t)row * 256 + 128 + cg + tx * 4);
            float4 hv = ld4(H + (size_t)row * 128 + cg + tx * 4);
            float n0 = tanhf(ai[i][0] + bi.x + rv.x * (ah[i][0] + bh.x));
            float n1 = tanhf(ai[i][1] + bi.y + rv.y * (ah[i][1] + bh.y));
            float n2 = tanhf(ai[i][2] + bi.z + rv.z * (ah[i][2] + bh.z));
            float n3 = tanhf(ai[i][3] + bi.w + rv.w * (ah[i][3] + bh.w));
            float4 o;
            o.x = (1.f - uv.x) * n0 + uv.x * hv.x;
            o.y = (1.f - uv.y) * n1 + uv.y * hv.y;
            o.z = (1.f - uv.z) * n2 + uv.z * hv.z;
            o.w = (1.f - uv.w) * n3 + uv.w * hv.w;
            *(float4*)&Hn[(size_t)row * 128 + cg + tx * 4] = o;
        }
    }
}

// ---------------------------------------------------------------------------
extern "C" void kernel_launch(void* const* d_in, const int* in_sizes, int n_in,
                              void* d_out, int out_size, void* d_ws, size_t ws_size,
                              hipStream_t stream) {
    const float* x   = (const float*)d_in[0];
    const int*   ei  = (const int*)d_in[1];
    const float* aW  = (const float*)d_in[2];
    const float* ab  = (const float*)d_in[3];
    const float* W1  = (const float*)d_in[4];
    const float* b1  = (const float*)d_in[5];
    const float* W2  = (const float*)d_in[6];
    const float* b2  = (const float*)d_in[7];
    const float* gam = (const float*)d_in[8];
    const float* bet = (const float*)d_in[9];
    const float* Wih = (const float*)d_in[10];
    const float* Whh = (const float*)d_in[11];
    const float* bih = (const float*)d_in[12];
    const float* bhh = (const float*)d_in[13];
    const float* lW1 = (const float*)d_in[14];
    const float* lb1 = (const float*)d_in[15];
    const float* lW2 = (const float*)d_in[16];
    const float* lb2 = (const float*)d_in[17];

    const int N = in_sizes[0] / 128;
    const int E = in_sizes[1] / 2;
    const int L = in_sizes[3] / 2;
    float* out = (float*)d_out;

    // workspace carve-up (~158 MB)
    char* ws = (char*)d_ws;
    size_t off = 0;
    auto alloc = [&](size_t bytes) -> void* {
        void* p = ws + off;
        off = (off + bytes + 255) & ~(size_t)255;
        return p;
    };
    int*   offs = (int*)alloc((size_t)(N + 1) * 4);
    int*   cur  = (int*)alloc((size_t)N * 4);
    int*   adj  = (int*)alloc((size_t)2 * E * 4);
    float* comb = (float*)alloc((size_t)N * 128 * 4);
    float* z1   = (float*)alloc((size_t)N * 128 * 4);
    float* hA   = (float*)alloc((size_t)N * 128 * 4);
    float* hB   = (float*)alloc((size_t)N * 128 * 4);
    float* ru   = (float*)alloc((size_t)N * 256 * 4);
    float* z    = comb;  // comb is dead once z1 exists; reuse for z
    (void)ws_size; (void)n_in; (void)out_size;

    hipMemsetAsync(cur, 0, (size_t)N * 4, stream);
    hipMemsetAsync(hA, 0, (size_t)N * 128 * 4, stream);

    k_deg<<<(E + 255) / 256, 256, 0, stream>>>(ei, cur, E);
    k_scan<<<1, 1024, 0, stream>>>(cur, offs, N);
    hipMemcpyAsync(cur, offs, (size_t)N * 4, hipMemcpyDeviceToDevice, stream);
    k_fill<<<(E + 255) / 256, 256, 0, stream>>>(ei, cur, adj, E);

    const int mb = (N + 63) / 64;
    const float* xin = x;
    float* hOld = hA;
    float* hNew = hB;
    for (int l = 0; l < L; ++l) {
        k_agg<<<(N + 3) / 4, 256, 0, stream>>>(xin, adj, offs, aW + (size_t)l * 512,
                                               ab + (size_t)l * 2, comb, N);
        k_gemm<1, false><<<dim3(mb, 2), 256, 0, stream>>>(
            comb, W1 + (size_t)l * 16384, b1 + (size_t)l * 128, nullptr, nullptr, z1, N, 128);
        k_gemm<0, true><<<dim3(mb, 2), 256, 0, stream>>>(
            z1, W2 + (size_t)l * 16384, b2 + (size_t)l * 128,
            gam + (size_t)l * 128, bet + (size_t)l * 128, z, N, 128);
        k_gru_ru<<<dim3(mb, 4), 256, 0, stream>>>(z, hOld, Wih, Whh, bih, bhh, ru, N);
        k_gru_nc<<<dim3(mb, 2), 256, 0, stream>>>(z, hOld, Wih, Whh, bih, bhh, ru, hNew, N);
        xin = hNew;
        float* tmp = hOld; hOld = hNew; hNew = tmp;
    }

    // final node MLP: relu(x @ lW1 + lb1) @ lW2 + lb2
    k_gemm<1, false><<<dim3(mb, 2), 256, 0, stream>>>(xin, lW1, lb1, nullptr, nullptr, z1, N, 128);
    k_gemm<0, false><<<dim3(mb, 1), 256, 0, stream>>>(z1, lW2, lb2, nullptr, nullptr, out, N, 64);
}

// Round 2
// 447.333 us; speedup vs baseline: 2.0580x; 2.0580x over previous
//
#include <hip/hip_runtime.h>
#include <math.h>

typedef unsigned short u16;
typedef __attribute__((ext_vector_type(8))) short bf16x8;
typedef __attribute__((ext_vector_type(4))) float f32x4;

__device__ __forceinline__ u16 f2b(float f) {
    union { float f; unsigned u; } v; v.f = f;
    unsigned r = (v.u + 0x7FFF + ((v.u >> 16) & 1)) >> 16;
    return (u16)r;
}
__device__ __forceinline__ float b2f(u16 h) {
    union { unsigned u; float f; } v; v.u = (unsigned)h << 16;
    return v.f;
}
__device__ __forceinline__ float fsig(float x) { return 1.f / (1.f + __expf(-x)); }
__device__ __forceinline__ float ftanh(float x) {
    float e = __expf(2.f * x);
    return 1.f - 2.f / (e + 1.f);
}

// ---------------- CSR build ----------------
__global__ void k_deg(const int* __restrict__ ei, int* __restrict__ cnt, int E) {
    int e = blockIdx.x * 256 + threadIdx.x;
    if (e < E) {
        atomicAdd(&cnt[ei[e]], 1);
        atomicAdd(&cnt[ei[E + e]], 1);
    }
}

__global__ __launch_bounds__(1024) void k_scan(const int* __restrict__ cnt,
                                               int* __restrict__ offs, int N) {
    __shared__ int sd[16];
    int t = threadIdx.x, lane = t & 63, wid = t >> 6;
    int carry = 0;
    if (t == 0) offs[0] = 0;
    for (int base = 0; base < N; base += 1024) {
        int v = (base + t < N) ? cnt[base + t] : 0;
        int inc = v;
#pragma unroll
        for (int o = 1; o < 64; o <<= 1) {
            int u = __shfl_up(inc, o);
            if (lane >= o) inc += u;
        }
        if (lane == 63) sd[wid] = inc;
        __syncthreads();
        if (wid == 0) {
            int wv = (lane < 16) ? sd[lane] : 0;
#pragma unroll
            for (int o = 1; o < 16; o <<= 1) {
                int u = __shfl_up(wv, o);
                if (lane >= o) wv += u;
            }
            if (lane < 16) sd[lane] = wv;  // inclusive wave sums
        }
        __syncthreads();
        int wbase = (wid > 0) ? sd[wid - 1] : 0;
        int total = sd[15];
        if (base + t < N) offs[base + t + 1] = carry + wbase + inc;
        carry += total;
        __syncthreads();
    }
}

__global__ void k_fill(const int* __restrict__ ei, int* __restrict__ cur,
                       int* __restrict__ adj, int E) {
    int e = blockIdx.x * 256 + threadIdx.x;
    if (e < E) {
        int s = ei[e], d = ei[E + e];
        int p = atomicAdd(&cur[s], 1); adj[p] = d;
        int q = atomicAdd(&cur[d], 1); adj[q] = s;
    }
}

// ---------------- weight prep: fp32 [K][NC] -> bf16 chunks [kslot][n][8] ----
__device__ __forceinline__ void conv_chunk(const float* __restrict__ src,
                                           u16* __restrict__ dst, int c, int NC) {
    int sl = c / NC, n = c - sl * NC;
    u16 tmp[8];
#pragma unroll
    for (int i = 0; i < 8; ++i) tmp[i] = f2b(src[(size_t)(sl * 8 + i) * NC + n]);
    *(uint4*)(dst + (size_t)c * 8) = *(const uint4*)tmp;
}

__global__ void k_prep_w(const float* __restrict__ W1, const float* __restrict__ W2,
                         const float* __restrict__ Wih, const float* __restrict__ Whh,
                         const float* __restrict__ lW1, const float* __restrict__ lW2,
                         u16* __restrict__ tW1, u16* __restrict__ tW2,
                         u16* __restrict__ tWih, u16* __restrict__ tWhh,
                         u16* __restrict__ tlW1, u16* __restrict__ tlW2, int L) {
    int c = blockIdx.x * 256 + threadIdx.x;
    if (c < L * 2048) { int l = c >> 11; conv_chunk(W1 + (size_t)l * 16384, tW1 + (size_t)l * 16384, c & 2047, 128); return; }
    c -= L * 2048;
    if (c < L * 2048) { int l = c >> 11; conv_chunk(W2 + (size_t)l * 16384, tW2 + (size_t)l * 16384, c & 2047, 128); return; }
    c -= L * 2048;
    if (c < 6144) { conv_chunk(Wih, tWih, c, 384); return; }
    c -= 6144;
    if (c < 6144) { conv_chunk(Whh, tWhh, c, 384); return; }
    c -= 6144;
    if (c < 2048) { conv_chunk(lW1, tlW1, c, 128); return; }
    c -= 2048;
    if (c < 1024) { conv_chunk(lW2, tlW2, c, 64); return; }
}

__global__ void k_f2b(const float* __restrict__ src, u16* __restrict__ dst, int n8) {
    int i = blockIdx.x * 256 + threadIdx.x;
    if (i < n8) {
        float4 a = *(const float4*)(src + (size_t)i * 8);
        float4 b = *(const float4*)(src + (size_t)i * 8 + 4);
        u16 t[8] = {f2b(a.x), f2b(a.y), f2b(a.z), f2b(a.w),
                    f2b(b.x), f2b(b.y), f2b(b.z), f2b(b.w)};
        *(uint4*)(dst + (size_t)i * 8) = *(const uint4*)t;
    }
}

// ---------------- aggregation + attention + comb (wave per node, bf16) -----
__global__ __launch_bounds__(256) void k_agg(const u16* __restrict__ xb,
                                             const int* __restrict__ adj,
                                             const int* __restrict__ offs,
                                             const float* __restrict__ aW,
                                             const float* __restrict__ ab,
                                             u16* __restrict__ comb, int N) {
    int n = blockIdx.x * 4 + (threadIdx.x >> 6);
    if (n >= N) return;
    int l = threadIdx.x & 63;
    int half = l >> 5, e0 = (l & 31) * 4;
    int beg = offs[n], end = offs[n + 1];
    float s[4] = {0.f, 0.f, 0.f, 0.f};
    float m[4] = {-3.402823e38f, -3.402823e38f, -3.402823e38f, -3.402823e38f};
    for (int j = beg + half; j < end; j += 2) {
        int nb = adj[j];
        ushort4 v = *(const ushort4*)(xb + (size_t)nb * 128 + e0);
        float f0 = b2f(v.x), f1 = b2f(v.y), f2 = b2f(v.z), f3 = b2f(v.w);
        s[0] += f0; s[1] += f1; s[2] += f2; s[3] += f3;
        m[0] = fmaxf(m[0], f0); m[1] = fmaxf(m[1], f1);
        m[2] = fmaxf(m[2], f2); m[3] = fmaxf(m[3], f3);
    }
#pragma unroll
    for (int i = 0; i < 4; ++i) {
        s[i] += __shfl_xor(s[i], 32);
        m[i] = fmaxf(m[i], __shfl_xor(m[i], 32));
    }
    if (beg == end) { m[0] = m[1] = m[2] = m[3] = 0.f; }
    float p0 = 0.f, p1 = 0.f;
#pragma unroll
    for (int i = 0; i < 4; ++i) {
        float2 wsv = *(const float2*)(aW + (size_t)(e0 + i) * 2);
        float2 wmv = *(const float2*)(aW + (size_t)(128 + e0 + i) * 2);
        p0 += s[i] * wsv.x + m[i] * wmv.x;
        p1 += s[i] * wsv.y + m[i] * wmv.y;
    }
#pragma unroll
    for (int o = 16; o; o >>= 1) { p0 += __shfl_xor(p0, o); p1 += __shfl_xor(p1, o); }
    p0 += ab[0]; p1 += ab[1];
    float pm = fmaxf(p0, p1);
    float ea = __expf(p0 - pm), eb = __expf(p1 - pm);
    float w0 = ea / (ea + eb), w1 = 1.f - w0;
    if (half == 0) {
        ushort4 xv = *(const ushort4*)(xb + (size_t)n * 128 + e0);
        ushort4 o;
        o.x = f2b(b2f(xv.x) + w0 * s[0] + w1 * m[0]);
        o.y = f2b(b2f(xv.y) + w0 * s[1] + w1 * m[1]);
        o.z = f2b(b2f(xv.z) + w0 * s[2] + w1 * m[2]);
        o.w = f2b(b2f(xv.w) + w0 * s[3] + w1 * m[3]);
        *(ushort4*)(comb + (size_t)n * 128 + e0) = o;
    }
}

// ---------------- MFMA GEMM: C = act/bn(A[M,128]@W[128,NC] + b) -------------
// A bf16 [M][128]; Wt bf16 chunks [16 kslots][NC][8]
template <int NC, int ACT, bool BN, bool OB, bool OF>
__global__ __launch_bounds__(256, 2) void k_mfma(const u16* __restrict__ A,
                                                 const u16* __restrict__ Wt,
                                                 const float* __restrict__ bias,
                                                 const float* __restrict__ gam,
                                                 const float* __restrict__ bet,
                                                 u16* __restrict__ Cb,
                                                 float* __restrict__ Cf, int M) {
    __shared__ __align__(16) u16 a_s[64 * 16 * 8];   // [row][slot^(row&7)][8]
    __shared__ __align__(16) u16 w_s[16 * NC * 8];   // [slot][col][8]
    const int t = threadIdx.x;
    const int m0 = blockIdx.x * 64;
    {
        int lin = t;
#pragma unroll
        for (int i = 0; i < 4; ++i, lin += 256) {
            int row = lin >> 4, sl = lin & 15;
            int gr = m0 + row; gr = gr < M ? gr : M - 1;
            uint4 v = *(const uint4*)(A + (size_t)gr * 128 + sl * 8);
            *(uint4*)&a_s[(row * 16 + (sl ^ (row & 7))) * 8] = v;
        }
    }
    {
        int lin = t;
#pragma unroll
        for (int i = 0; i < NC / 16; ++i, lin += 256) {
            uint4 v = *(const uint4*)(Wt + (size_t)lin * 8);
            *(uint4*)&w_s[lin * 8] = v;
        }
    }
    __syncthreads();
    const int w = t >> 6, l = t & 63, lo = l & 15, hi = l >> 4;
    f32x4 acc[NC / 16];
#pragma unroll
    for (int j = 0; j < NC / 16; ++j) acc[j] = (f32x4)0.f;
    const int arow = 16 * w + lo;
#pragma unroll
    for (int ks = 0; ks < 4; ++ks) {
        bf16x8 af = *(const bf16x8*)&a_s[(arow * 16 + ((ks * 4 + hi) ^ (arow & 7))) * 8];
#pragma unroll
        for (int j = 0; j < NC / 16; ++j) {
            bf16x8 bf = *(const bf16x8*)&w_s[((ks * 4 + hi) * NC + 16 * j + lo) * 8];
            acc[j] = __builtin_amdgcn_mfma_f32_16x16x32_bf16(af, bf, acc[j], 0, 0, 0);
        }
    }
#pragma unroll
    for (int j = 0; j < NC / 16; ++j) {
        int c = 16 * j + lo;
        float bv = bias[c];
        float gv = 1.f, tv = 0.f;
        if (BN) { gv = gam[c]; tv = bet[c]; }
#pragma unroll
        for (int q = 0; q < 4; ++q) {
            int r = m0 + 16 * w + hi * 4 + q;
            if (r < M) {
                float v = acc[j][q] + bv;
                if (BN) v = v * gv + tv;
                if (ACT) v = fmaxf(v, 0.f);
                if (OB) Cb[(size_t)r * NC + c] = f2b(v);
                if (OF) Cf[(size_t)r * NC + c] = v;
            }
        }
    }
}

// ---------------- fused GRU: all 3 gates + update, one pass -----------------
// Zb,Hb bf16 [M][128]; Hf fp32 [M][128]; Wit,Wht bf16 chunks [16][384][8]
__global__ __launch_bounds__(256, 2) void k_gru(const u16* __restrict__ Zb,
                                                const u16* __restrict__ Hb,
                                                const float* __restrict__ Hf,
                                                const u16* __restrict__ Wit,
                                                const u16* __restrict__ Wht,
                                                const float* __restrict__ bih,
                                                const float* __restrict__ bhh,
                                                float* __restrict__ Hn,
                                                u16* __restrict__ Hnb, int M) {
    __shared__ __align__(16) u16 z_s[64 * 4 * 8], h_s[64 * 4 * 8];
    __shared__ __align__(16) u16 wi_s[4 * 384 * 8], wh_s[4 * 384 * 8];
    const int t = threadIdx.x;
    const int m0 = blockIdx.x * 64;
    const int w = t >> 6, l = t & 63, lo = l & 15, hi = l >> 4;
    f32x4 aru[16], ain[8], ahn[8];
#pragma unroll
    for (int j = 0; j < 16; ++j) aru[j] = (f32x4)0.f;
#pragma unroll
    for (int j = 0; j < 8; ++j) { ain[j] = (f32x4)0.f; ahn[j] = (f32x4)0.f; }

    for (int kc = 0; kc < 4; ++kc) {
        {   // stage A chunks (64 rows x 4 slots), XOR swizzle within 4
            int row = t >> 2, sl = t & 3;
            int gr = m0 + row; gr = gr < M ? gr : M - 1;
            uint4 vz = *(const uint4*)(Zb + (size_t)gr * 128 + (kc * 4 + sl) * 8);
            uint4 vh = *(const uint4*)(Hb + (size_t)gr * 128 + (kc * 4 + sl) * 8);
            int d = (row * 4 + (sl ^ (row & 3))) * 8;
            *(uint4*)&z_s[d] = vz;
            *(uint4*)&h_s[d] = vh;
        }
        {   // stage weight chunks [4 slots][384][8] linear
#pragma unroll
            for (int i = 0; i < 6; ++i) {
                int c = t + i * 256;
                int sl = c / 384, n = c - sl * 384;
                uint4 vi = *(const uint4*)(Wit + ((size_t)(kc * 4 + sl) * 384 + n) * 8);
                uint4 vh = *(const uint4*)(Wht + ((size_t)(kc * 4 + sl) * 384 + n) * 8);
                int d = (sl * 384 + n) * 8;
                *(uint4*)&wi_s[d] = vi;
                *(uint4*)&wh_s[d] = vh;
            }
        }
        __syncthreads();
        const int arow = 16 * w + lo;
        const int ad = (arow * 4 + (hi ^ (arow & 3))) * 8;
        bf16x8 zf = *(const bf16x8*)&z_s[ad];
        bf16x8 hf = *(const bf16x8*)&h_s[ad];
#pragma unroll
        for (int j = 0; j < 24; ++j) {
            int wd = (hi * 384 + 16 * j + lo) * 8;
            bf16x8 bi_ = *(const bf16x8*)&wi_s[wd];
            bf16x8 bh_ = *(const bf16x8*)&wh_s[wd];
            if (j < 16) {
                aru[j] = __builtin_amdgcn_mfma_f32_16x16x32_bf16(zf, bi_, aru[j], 0, 0, 0);
                aru[j] = __builtin_amdgcn_mfma_f32_16x16x32_bf16(hf, bh_, aru[j], 0, 0, 0);
            } else {
                ain[j - 16] = __builtin_amdgcn_mfma_f32_16x16x32_bf16(zf, bi_, ain[j - 16], 0, 0, 0);
                ahn[j - 16] = __builtin_amdgcn_mfma_f32_16x16x32_bf16(hf, bh_, ahn[j - 16], 0, 0, 0);
            }
        }
        __syncthreads();
    }
#pragma unroll
    for (int j = 0; j < 8; ++j) {
        int c = 16 * j + lo;
        float b_r = bih[c] + bhh[c];
        float b_u = bih[c + 128] + bhh[c + 128];
        float b_in = bih[c + 256], b_hn = bhh[c + 256];
#pragma unroll
        for (int q = 0; q < 4; ++q) {
            int r = m0 + 16 * w + hi * 4 + q;
            if (r < M) {
                float rr = fsig(aru[j][q] + b_r);
                float uu = fsig(aru[j + 8][q] + b_u);
                float nn = ftanh(ain[j][q] + b_in + rr * (ahn[j][q] + b_hn));
                float hv = Hf[(size_t)r * 128 + c];
                float o = (1.f - uu) * nn + uu * hv;
                Hn[(size_t)r * 128 + c] = o;
                Hnb[(size_t)r * 128 + c] = f2b(o);
            }
        }
    }
}

// ---------------------------------------------------------------------------
extern "C" void kernel_launch(void* const* d_in, const int* in_sizes, int n_in,
                              void* d_out, int out_size, void* d_ws, size_t ws_size,
                              hipStream_t stream) {
    const float* x   = (const float*)d_in[0];
    const int*   ei  = (const int*)d_in[1];
    const float* aW  = (const float*)d_in[2];
    const float* ab  = (const float*)d_in[3];
    const float* W1  = (const float*)d_in[4];
    const float* b1  = (const float*)d_in[5];
    const float* W2  = (const float*)d_in[6];
    const float* b2  = (const float*)d_in[7];
    const float* gam = (const float*)d_in[8];
    const float* bet = (const float*)d_in[9];
    const float* Wih = (const float*)d_in[10];
    const float* Whh = (const float*)d_in[11];
    const float* bih = (const float*)d_in[12];
    const float* bhh = (const float*)d_in[13];
    const float* lW1 = (const float*)d_in[14];
    const float* lb1 = (const float*)d_in[15];
    const float* lW2 = (const float*)d_in[16];
    const float* lb2 = (const float*)d_in[17];

    const int N = in_sizes[0] / 128;
    const int E = in_sizes[1] / 2;
    const int L = in_sizes[3] / 2;
    float* out = (float*)d_out;

    char* ws = (char*)d_ws;
    size_t off = 0;
    auto alloc = [&](size_t bytes) -> void* {
        void* p = ws + off;
        off = (off + bytes + 255) & ~(size_t)255;
        return p;
    };
    int* offs = (int*)alloc((size_t)(N + 1) * 4);
    int* cur  = (int*)alloc((size_t)N * 4);
    int* adj  = (int*)alloc((size_t)2 * E * 4);
    u16* tW1  = (u16*)alloc((size_t)L * 16384 * 2);
    u16* tW2  = (u16*)alloc((size_t)L * 16384 * 2);
    u16* tWih = (u16*)alloc((size_t)49152 * 2);
    u16* tWhh = (u16*)alloc((size_t)49152 * 2);
    u16* tlW1 = (u16*)alloc((size_t)16384 * 2);
    u16* tlW2 = (u16*)alloc((size_t)8192 * 2);
    u16* xb   = (u16*)alloc((size_t)N * 128 * 2);
    u16* comb = (u16*)alloc((size_t)N * 128 * 2);
    u16* z1b  = (u16*)alloc((size_t)N * 128 * 2);
    u16* zb   = (u16*)alloc((size_t)N * 128 * 2);
    float* hA = (float*)alloc((size_t)N * 128 * 4);
    float* hB = (float*)alloc((size_t)N * 128 * 4);
    u16* hAb  = (u16*)alloc((size_t)N * 128 * 2);
    u16* hBb  = (u16*)alloc((size_t)N * 128 * 2);
    (void)ws_size; (void)n_in; (void)out_size;

    hipMemsetAsync(cur, 0, (size_t)N * 4, stream);
    hipMemsetAsync(hA, 0, (size_t)N * 128 * 4, stream);
    hipMemsetAsync(hAb, 0, (size_t)N * 128 * 2, stream);

    // prep
    int wchunks = L * 4096 + 12288 + 3072;
    k_prep_w<<<(wchunks + 255) / 256, 256, 0, stream>>>(W1, W2, Wih, Whh, lW1, lW2,
                                                        tW1, tW2, tWih, tWhh, tlW1, tlW2, L);
    k_f2b<<<(N * 16 + 255) / 256, 256, 0, stream>>>(x, xb, N * 16);

    // CSR
    k_deg<<<(E + 255) / 256, 256, 0, stream>>>(ei, cur, E);
    k_scan<<<1, 1024, 0, stream>>>(cur, offs, N);
    hipMemcpyAsync(cur, offs, (size_t)N * 4, hipMemcpyDeviceToDevice, stream);
    k_fill<<<(E + 255) / 256, 256, 0, stream>>>(ei, cur, adj, E);

    const int mb = (N + 63) / 64;
    const u16* xin_b = xb;
    float* hfOld = hA; float* hfNew = hB;
    u16* hbOld = hAb; u16* hbNew = hBb;
    for (int l = 0; l < L; ++l) {
        k_agg<<<(N + 3) / 4, 256, 0, stream>>>(xin_b, adj, offs, aW + (size_t)l * 512,
                                               ab + (size_t)l * 2, comb, N);
        k_mfma<128, 1, false, true, false><<<mb, 256, 0, stream>>>(
            comb, tW1 + (size_t)l * 16384, b1 + (size_t)l * 128, nullptr, nullptr,
            z1b, nullptr, N);
        k_mfma<128, 0, true, true, false><<<mb, 256, 0, stream>>>(
            z1b, tW2 + (size_t)l * 16384, b2 + (size_t)l * 128,
            gam + (size_t)l * 128, bet + (size_t)l * 128, zb, nullptr, N);
        k_gru<<<mb, 256, 0, stream>>>(zb, hbOld, hfOld, tWih, tWhh, bih, bhh,
                                      hfNew, hbNew, N);
        xin_b = hbNew;
        { float* tf = hfOld; hfOld = hfNew; hfNew = tf; }
        { u16* tb = hbOld; hbOld = hbNew; hbNew = tb; }
    }

    // final MLP: relu(h @ lW1 + lb1) @ lW2 + lb2
    k_mfma<128, 1, false, true, false><<<mb, 256, 0, stream>>>(
        hbOld, tlW1, lb1, nullptr, nullptr, z1b, nullptr, N);
    k_mfma<64, 0, false, false, true><<<mb, 256, 0, stream>>>(
        z1b, tlW2, lb2, nullptr, nullptr, nullptr, out, N);
}

// Round 3
// 284.435 us; speedup vs baseline: 3.2366x; 1.5727x over previous
//
#include <hip/hip_runtime.h>
#include <math.h>

typedef unsigned short u16;
typedef __attribute__((ext_vector_type(8))) short bf16x8;
typedef __attribute__((ext_vector_type(4))) float f32x4;

__device__ __forceinline__ u16 f2b(float f) {
    union { float f; unsigned u; } v; v.f = f;
    unsigned r = (v.u + 0x7FFF + ((v.u >> 16) & 1)) >> 16;
    return (u16)r;
}
__device__ __forceinline__ float b2f(u16 h) {
    union { unsigned u; float f; } v; v.u = (unsigned)h << 16;
    return v.f;
}
__device__ __forceinline__ float fsig(float x) { return 1.f / (1.f + __expf(-x)); }
__device__ __forceinline__ float ftanh(float x) {
    float e = __expf(2.f * x);
    return 1.f - 2.f / (e + 1.f);
}

// ---------------- CSR build ----------------
__global__ void k_deg(const int* __restrict__ ei, int* __restrict__ cnt, int E) {
    int e = blockIdx.x * 256 + threadIdx.x;
    if (e < E) {
        atomicAdd(&cnt[ei[e]], 1);
        atomicAdd(&cnt[ei[E + e]], 1);
    }
}

__global__ __launch_bounds__(1024) void k_scan_sum(const int* __restrict__ cnt,
                                                   int* __restrict__ part, int N) {
    __shared__ int sd[16];
    int t = threadIdx.x;
    int i = blockIdx.x * 1024 + t;
    int v = (i < N) ? cnt[i] : 0;
#pragma unroll
    for (int o = 32; o; o >>= 1) v += __shfl_xor(v, o);
    if ((t & 63) == 0) sd[t >> 6] = v;
    __syncthreads();
    if (t < 16) {
        int s = sd[t];
#pragma unroll
        for (int o = 8; o; o >>= 1) s += __shfl_xor(s, o);
        if (t == 0) part[blockIdx.x] = s;
    }
}

__global__ void k_scan_part(int* __restrict__ part, int nb) {
    int t = threadIdx.x;
    int v = (t < nb) ? part[t] : 0;
#pragma unroll
    for (int o = 1; o < 64; o <<= 1) {
        int u = __shfl_up(v, o);
        if ((t & 63) >= o) v += u;
    }
    if (t < nb) part[t] = v;  // inclusive scan of block sums
}

__global__ __launch_bounds__(1024) void k_scan_write(const int* __restrict__ cnt,
                                                     const int* __restrict__ part,
                                                     int* __restrict__ offs, int N) {
    __shared__ int sd[16];
    int t = threadIdx.x, lane = t & 63, wid = t >> 6;
    int i = blockIdx.x * 1024 + t;
    int v = (i < N) ? cnt[i] : 0;
    int inc = v;
#pragma unroll
    for (int o = 1; o < 64; o <<= 1) {
        int u = __shfl_up(inc, o);
        if (lane >= o) inc += u;
    }
    if (lane == 63) sd[wid] = inc;
    __syncthreads();
    if (wid == 0) {
        int wv = (lane < 16) ? sd[lane] : 0;
#pragma unroll
        for (int o = 1; o < 16; o <<= 1) {
            int u = __shfl_up(wv, o);
            if (lane >= o) wv += u;
        }
        if (lane < 16) sd[lane] = wv;
    }
    __syncthreads();
    int base = (blockIdx.x > 0 ? part[blockIdx.x - 1] : 0) + (wid > 0 ? sd[wid - 1] : 0);
    if (i < N) offs[i + 1] = base + inc;
    if (i == 0 && blockIdx.x == 0) offs[0] = 0;
}

__global__ void k_fill(const int* __restrict__ ei, int* __restrict__ cur,
                       u16* __restrict__ adj, int E) {
    int e = blockIdx.x * 256 + threadIdx.x;
    if (e < E) {
        int s = ei[e], d = ei[E + e];
        int p = atomicAdd(&cur[s], 1); adj[p] = (u16)d;
        int q = atomicAdd(&cur[d], 1); adj[q] = (u16)s;
    }
}

// ---------------- weight prep: fp32 [K][NC] -> bf16 chunks [kslot][n][8] ----
__device__ __forceinline__ void conv_chunk(const float* __restrict__ src,
                                           u16* __restrict__ dst, int c, int NC) {
    int sl = c / NC, n = c - sl * NC;
    u16 tmp[8];
#pragma unroll
    for (int i = 0; i < 8; ++i) tmp[i] = f2b(src[(size_t)(sl * 8 + i) * NC + n]);
    *(uint4*)(dst + (size_t)c * 8) = *(const uint4*)tmp;
}

__global__ void k_prep_w(const float* __restrict__ W1, const float* __restrict__ W2,
                         const float* __restrict__ Wih, const float* __restrict__ Whh,
                         const float* __restrict__ lW1, const float* __restrict__ lW2,
                         u16* __restrict__ tW1, u16* __restrict__ tW2,
                         u16* __restrict__ tWih, u16* __restrict__ tWhh,
                         u16* __restrict__ tlW1, u16* __restrict__ tlW2, int L) {
    int c = blockIdx.x * 256 + threadIdx.x;
    if (c < L * 2048) { int l = c >> 11; conv_chunk(W1 + (size_t)l * 16384, tW1 + (size_t)l * 16384, c & 2047, 128); return; }
    c -= L * 2048;
    if (c < L * 2048) { int l = c >> 11; conv_chunk(W2 + (size_t)l * 16384, tW2 + (size_t)l * 16384, c & 2047, 128); return; }
    c -= L * 2048;
    if (c < 6144) { conv_chunk(Wih, tWih, c, 384); return; }
    c -= 6144;
    if (c < 6144) { conv_chunk(Whh, tWhh, c, 384); return; }
    c -= 6144;
    if (c < 2048) { conv_chunk(lW1, tlW1, c, 128); return; }
    c -= 2048;
    if (c < 1024) { conv_chunk(lW2, tlW2, c, 64); return; }
}

__global__ void k_f2b(const float* __restrict__ src, u16* __restrict__ dst, int n8) {
    int i = blockIdx.x * 256 + threadIdx.x;
    if (i < n8) {
        float4 a = *(const float4*)(src + (size_t)i * 8);
        float4 b = *(const float4*)(src + (size_t)i * 8 + 4);
        u16 t[8] = {f2b(a.x), f2b(a.y), f2b(a.z), f2b(a.w),
                    f2b(b.x), f2b(b.y), f2b(b.z), f2b(b.w)};
        *(uint4*)(dst + (size_t)i * 8) = *(const uint4*)t;
    }
}

// ---------------- aggregation + attention + comb (wave per node) -----------
__global__ __launch_bounds__(256) void k_agg(const u16* __restrict__ xb,
                                             const u16* __restrict__ adj,
                                             const int* __restrict__ offs,
                                             const float* __restrict__ aW,
                                             const float* __restrict__ ab,
                                             u16* __restrict__ comb, int N) {
    int n = blockIdx.x * 4 + (threadIdx.x >> 6);
    if (n >= N) return;
    int l = threadIdx.x & 63;
    int half = l >> 5, e0 = (l & 31) * 4;
    int beg = offs[n], end = offs[n + 1];
    float s0 = 0.f, s1 = 0.f, s2 = 0.f, s3 = 0.f;
    float m0 = -3.402823e38f, m1 = m0, m2 = m0, m3 = m0;
    int j = beg + half;
    for (; j + 6 < end; j += 8) {
        int a0 = adj[j], a1 = adj[j + 2], a2 = adj[j + 4], a3 = adj[j + 6];
        ushort4 v0 = *(const ushort4*)(xb + (size_t)a0 * 128 + e0);
        ushort4 v1 = *(const ushort4*)(xb + (size_t)a1 * 128 + e0);
        ushort4 v2 = *(const ushort4*)(xb + (size_t)a2 * 128 + e0);
        ushort4 v3 = *(const ushort4*)(xb + (size_t)a3 * 128 + e0);
        float f0, f1, f2, f3;
        f0 = b2f(v0.x); f1 = b2f(v0.y); f2 = b2f(v0.z); f3 = b2f(v0.w);
        s0 += f0; s1 += f1; s2 += f2; s3 += f3;
        m0 = fmaxf(m0, f0); m1 = fmaxf(m1, f1); m2 = fmaxf(m2, f2); m3 = fmaxf(m3, f3);
        f0 = b2f(v1.x); f1 = b2f(v1.y); f2 = b2f(v1.z); f3 = b2f(v1.w);
        s0 += f0; s1 += f1; s2 += f2; s3 += f3;
        m0 = fmaxf(m0, f0); m1 = fmaxf(m1, f1); m2 = fmaxf(m2, f2); m3 = fmaxf(m3, f3);
        f0 = b2f(v2.x); f1 = b2f(v2.y); f2 = b2f(v2.z); f3 = b2f(v2.w);
        s0 += f0; s1 += f1; s2 += f2; s3 += f3;
        m0 = fmaxf(m0, f0); m1 = fmaxf(m1, f1); m2 = fmaxf(m2, f2); m3 = fmaxf(m3, f3);
        f0 = b2f(v3.x); f1 = b2f(v3.y); f2 = b2f(v3.z); f3 = b2f(v3.w);
        s0 += f0; s1 += f1; s2 += f2; s3 += f3;
        m0 = fmaxf(m0, f0); m1 = fmaxf(m1, f1); m2 = fmaxf(m2, f2); m3 = fmaxf(m3, f3);
    }
    for (; j < end; j += 2) {
        int nb = adj[j];
        ushort4 v = *(const ushort4*)(xb + (size_t)nb * 128 + e0);
        float f0 = b2f(v.x), f1 = b2f(v.y), f2 = b2f(v.z), f3 = b2f(v.w);
        s0 += f0; s1 += f1; s2 += f2; s3 += f3;
        m0 = fmaxf(m0, f0); m1 = fmaxf(m1, f1); m2 = fmaxf(m2, f2); m3 = fmaxf(m3, f3);
    }
    s0 += __shfl_xor(s0, 32); m0 = fmaxf(m0, __shfl_xor(m0, 32));
    s1 += __shfl_xor(s1, 32); m1 = fmaxf(m1, __shfl_xor(m1, 32));
    s2 += __shfl_xor(s2, 32); m2 = fmaxf(m2, __shfl_xor(m2, 32));
    s3 += __shfl_xor(s3, 32); m3 = fmaxf(m3, __shfl_xor(m3, 32));
    if (beg == end) { m0 = m1 = m2 = m3 = 0.f; }
    float p0 = 0.f, p1 = 0.f;
    {
        float2 w0v = *(const float2*)(aW + (size_t)e0 * 2);
        float2 w1v = *(const float2*)(aW + (size_t)(e0 + 1) * 2);
        float2 w2v = *(const float2*)(aW + (size_t)(e0 + 2) * 2);
        float2 w3v = *(const float2*)(aW + (size_t)(e0 + 3) * 2);
        float2 u0v = *(const float2*)(aW + (size_t)(128 + e0) * 2);
        float2 u1v = *(const float2*)(aW + (size_t)(128 + e0 + 1) * 2);
        float2 u2v = *(const float2*)(aW + (size_t)(128 + e0 + 2) * 2);
        float2 u3v = *(const float2*)(aW + (size_t)(128 + e0 + 3) * 2);
        p0 = s0 * w0v.x + s1 * w1v.x + s2 * w2v.x + s3 * w3v.x
           + m0 * u0v.x + m1 * u1v.x + m2 * u2v.x + m3 * u3v.x;
        p1 = s0 * w0v.y + s1 * w1v.y + s2 * w2v.y + s3 * w3v.y
           + m0 * u0v.y + m1 * u1v.y + m2 * u2v.y + m3 * u3v.y;
    }
#pragma unroll
    for (int o = 16; o; o >>= 1) { p0 += __shfl_xor(p0, o); p1 += __shfl_xor(p1, o); }
    p0 += ab[0]; p1 += ab[1];
    float pm = fmaxf(p0, p1);
    float ea = __expf(p0 - pm), eb = __expf(p1 - pm);
    float w0 = ea / (ea + eb), w1 = 1.f - w0;
    if (half == 0) {
        ushort4 xv = *(const ushort4*)(xb + (size_t)n * 128 + e0);
        ushort4 o;
        o.x = f2b(b2f(xv.x) + w0 * s0 + w1 * m0);
        o.y = f2b(b2f(xv.y) + w0 * s1 + w1 * m1);
        o.z = f2b(b2f(xv.z) + w0 * s2 + w1 * m2);
        o.w = f2b(b2f(xv.w) + w0 * s3 + w1 * m3);
        *(ushort4*)(comb + (size_t)n * 128 + e0) = o;
    }
}

// ---------------- fused layer: MLP1 -> MLP2+BN -> GRU ----------------------
// 128 rows/block, 512 threads. A stays in LDS; weights chunk-staged.
template <bool H0, bool WF32>
__global__ __launch_bounds__(512, 2) void k_layer(
    const u16* __restrict__ Cb, const u16* __restrict__ Hb,
    const float* __restrict__ Hf,
    const u16* __restrict__ W1t, const float* __restrict__ b1,
    const u16* __restrict__ W2t, const float* __restrict__ b2,
    const float* __restrict__ gam, const float* __restrict__ bet,
    const u16* __restrict__ Wit, const u16* __restrict__ Wht,
    const float* __restrict__ bih, const float* __restrict__ bhh,
    float* __restrict__ HnF, u16* __restrict__ HnB, int M) {
    __shared__ __align__(16) u16 x_s[128 * 16 * 8];   // 32KB: comb -> z1 -> z
    __shared__ __align__(16) u16 h_s[128 * 16 * 8];   // 32KB: prev h (unused if H0)
    __shared__ __align__(16) u16 w_s[24576];          // 48KB: W1/W2 (32KB) or Wih|Whh chunks
    const int t = threadIdx.x;
    const int m0 = blockIdx.x * 128;
    const int w = t >> 6, l = t & 63, lo = l & 15, hi = l >> 4;
    const int arow = 16 * w + lo;

    // ---- stage comb, (h), W1
#pragma unroll
    for (int i = 0; i < 4; ++i) {
        int idx = t + i * 512;
        int row = idx >> 4, sl = idx & 15;
        int gr = m0 + row; gr = gr < M ? gr : M - 1;
        int d = (row * 16 + (sl ^ (row & 7))) * 8;
        *(uint4*)&x_s[d] = *(const uint4*)(Cb + (size_t)gr * 128 + sl * 8);
        if (!H0) *(uint4*)&h_s[d] = *(const uint4*)(Hb + (size_t)gr * 128 + sl * 8);
    }
#pragma unroll
    for (int i = 0; i < 4; ++i) {
        int idx = t + i * 512;
        *(uint4*)&w_s[idx * 8] = *(const uint4*)(W1t + (size_t)idx * 8);
    }
    __syncthreads();

    f32x4 acc[8];
    // ---- GEMM1: z1 = relu(comb @ W1 + b1)
#pragma unroll
    for (int j = 0; j < 8; ++j) acc[j] = (f32x4)0.f;
#pragma unroll
    for (int ks = 0; ks < 4; ++ks) {
        bf16x8 af = *(const bf16x8*)&x_s[(arow * 16 + ((ks * 4 + hi) ^ (arow & 7))) * 8];
#pragma unroll
        for (int j = 0; j < 8; ++j) {
            bf16x8 bf = *(const bf16x8*)&w_s[((ks * 4 + hi) * 128 + 16 * j + lo) * 8];
            acc[j] = __builtin_amdgcn_mfma_f32_16x16x32_bf16(af, bf, acc[j], 0, 0, 0);
        }
    }
    __syncthreads();
    // write z1 -> x_s; stage W2
#pragma unroll
    for (int j = 0; j < 8; ++j) {
        int c = 16 * j + lo;
        float bv = b1[c];
#pragma unroll
        for (int q = 0; q < 4; ++q) {
            int row = 16 * w + hi * 4 + q;
            float v = fmaxf(acc[j][q] + bv, 0.f);
            int sl = c >> 3;
            x_s[(row * 16 + (sl ^ (row & 7))) * 8 + (c & 7)] = f2b(v);
        }
    }
#pragma unroll
    for (int i = 0; i < 4; ++i) {
        int idx = t + i * 512;
        *(uint4*)&w_s[idx * 8] = *(const uint4*)(W2t + (size_t)idx * 8);
    }
    __syncthreads();

    // ---- GEMM2: z = (z1 @ W2 + b2) * gam + bet
#pragma unroll
    for (int j = 0; j < 8; ++j) acc[j] = (f32x4)0.f;
#pragma unroll
    for (int ks = 0; ks < 4; ++ks) {
        bf16x8 af = *(const bf16x8*)&x_s[(arow * 16 + ((ks * 4 + hi) ^ (arow & 7))) * 8];
#pragma unroll
        for (int j = 0; j < 8; ++j) {
            bf16x8 bf = *(const bf16x8*)&w_s[((ks * 4 + hi) * 128 + 16 * j + lo) * 8];
            acc[j] = __builtin_amdgcn_mfma_f32_16x16x32_bf16(af, bf, acc[j], 0, 0, 0);
        }
    }
    __syncthreads();
    // write z -> x_s; stage GRU chunk 0 (Wih|Whh, K=32 each)
#pragma unroll
    for (int j = 0; j < 8; ++j) {
        int c = 16 * j + lo;
        float bv = b2[c], gv = gam[c], tv = bet[c];
#pragma unroll
        for (int q = 0; q < 4; ++q) {
            int row = 16 * w + hi * 4 + q;
            float v = (acc[j][q] + bv) * gv + tv;
            int sl = c >> 3;
            x_s[(row * 16 + (sl ^ (row & 7))) * 8 + (c & 7)] = f2b(v);
        }
    }
#pragma unroll
    for (int i = 0; i < 3; ++i) {
        int idx = t + i * 512;
        *(uint4*)&w_s[idx * 8] = *(const uint4*)(Wit + (size_t)idx * 8);
        *(uint4*)&w_s[12288 + idx * 8] = *(const uint4*)(Wht + (size_t)idx * 8);
    }
    __syncthreads();

    // ---- GRU: gi = z@Wih, gh = h@Whh over 4 K-chunks
    f32x4 aru[16], ain[8], ahn[8];
#pragma unroll
    for (int j = 0; j < 16; ++j) aru[j] = (f32x4)0.f;
#pragma unroll
    for (int j = 0; j < 8; ++j) { ain[j] = (f32x4)0.f; ahn[j] = (f32x4)0.f; }
    for (int kc = 0; kc < 4; ++kc) {
        bf16x8 zf = *(const bf16x8*)&x_s[(arow * 16 + ((kc * 4 + hi) ^ (arow & 7))) * 8];
        bf16x8 hf;
        if (!H0) hf = *(const bf16x8*)&h_s[(arow * 16 + ((kc * 4 + hi) ^ (arow & 7))) * 8];
#pragma unroll
        for (int j = 0; j < 24; ++j) {
            bf16x8 bi_ = *(const bf16x8*)&w_s[(hi * 384 + 16 * j + lo) * 8];
            if (j < 16) {
                aru[j] = __builtin_amdgcn_mfma_f32_16x16x32_bf16(zf, bi_, aru[j], 0, 0, 0);
            } else {
                ain[j - 16] = __builtin_amdgcn_mfma_f32_16x16x32_bf16(zf, bi_, ain[j - 16], 0, 0, 0);
            }
            if (!H0) {
                bf16x8 bh_ = *(const bf16x8*)&w_s[12288 + (hi * 384 + 16 * j + lo) * 8];
                if (j < 16) {
                    aru[j] = __builtin_amdgcn_mfma_f32_16x16x32_bf16(hf, bh_, aru[j], 0, 0, 0);
                } else {
                    ahn[j - 16] = __builtin_amdgcn_mfma_f32_16x16x32_bf16(hf, bh_, ahn[j - 16], 0, 0, 0);
                }
            }
        }
        __syncthreads();
        if (kc < 3) {
#pragma unroll
            for (int i = 0; i < 3; ++i) {
                int idx = t + i * 512;
                *(uint4*)&w_s[idx * 8] = *(const uint4*)(Wit + (size_t)((kc + 1) * 1536 + idx) * 8);
                *(uint4*)&w_s[12288 + idx * 8] = *(const uint4*)(Wht + (size_t)((kc + 1) * 1536 + idx) * 8);
            }
            __syncthreads();
        }
    }

    // ---- gates + hidden update
#pragma unroll
    for (int j = 0; j < 8; ++j) {
        int c = 16 * j + lo;
        float b_r = bih[c] + bhh[c];
        float b_u = bih[c + 128] + bhh[c + 128];
        float b_in = bih[c + 256], b_hn = bhh[c + 256];
#pragma unroll
        for (int q = 0; q < 4; ++q) {
            int r = m0 + 16 * w + hi * 4 + q;
            if (r < M) {
                float rr = fsig(aru[j][q] + b_r);
                float uu = fsig(aru[j + 8][q] + b_u);
                float hterm = H0 ? b_hn : (ahn[j][q] + b_hn);
                float nn = ftanh(ain[j][q] + b_in + rr * hterm);
                float hv = H0 ? 0.f : Hf[(size_t)r * 128 + c];
                float o = (1.f - uu) * nn + uu * hv;
                if (WF32) HnF[(size_t)r * 128 + c] = o;
                HnB[(size_t)r * 128 + c] = f2b(o);
            }
        }
    }
}

// ---------------- fused final MLP: out = relu(h@lW1+lb1)@lW2 + lb2 --------
__global__ __launch_bounds__(256, 2) void k_final(const u16* __restrict__ Hb,
                                                  const u16* __restrict__ W1t,
                                                  const float* __restrict__ b1,
                                                  const u16* __restrict__ W2t,
                                                  const float* __restrict__ b2,
                                                  float* __restrict__ out, int M) {
    __shared__ __align__(16) u16 x_s[64 * 16 * 8];    // 16KB
    __shared__ __align__(16) u16 w_s[16 * 128 * 8];   // 32KB
    const int t = threadIdx.x;
    const int m0 = blockIdx.x * 64;
    const int w = t >> 6, l = t & 63, lo = l & 15, hi = l >> 4;
    const int arow = 16 * w + lo;
#pragma unroll
    for (int i = 0; i < 4; ++i) {
        int idx = t + i * 256;
        int row = idx >> 4, sl = idx & 15;
        int gr = m0 + row; gr = gr < M ? gr : M - 1;
        *(uint4*)&x_s[(row * 16 + (sl ^ (row & 7))) * 8] =
            *(const uint4*)(Hb + (size_t)gr * 128 + sl * 8);
    }
#pragma unroll
    for (int i = 0; i < 8; ++i) {
        int idx = t + i * 256;
        *(uint4*)&w_s[idx * 8] = *(const uint4*)(W1t + (size_t)idx * 8);
    }
    __syncthreads();
    f32x4 acc[8];
#pragma unroll
    for (int j = 0; j < 8; ++j) acc[j] = (f32x4)0.f;
#pragma unroll
    for (int ks = 0; ks < 4; ++ks) {
        bf16x8 af = *(const bf16x8*)&x_s[(arow * 16 + ((ks * 4 + hi) ^ (arow & 7))) * 8];
#pragma unroll
        for (int j = 0; j < 8; ++j) {
            bf16x8 bf = *(const bf16x8*)&w_s[((ks * 4 + hi) * 128 + 16 * j + lo) * 8];
            acc[j] = __builtin_amdgcn_mfma_f32_16x16x32_bf16(af, bf, acc[j], 0, 0, 0);
        }
    }
    __syncthreads();
#pragma unroll
    for (int j = 0; j < 8; ++j) {
        int c = 16 * j + lo;
        float bv = b1[c];
#pragma unroll
        for (int q = 0; q < 4; ++q) {
            int row = 16 * w + hi * 4 + q;
            float v = fmaxf(acc[j][q] + bv, 0.f);
            int sl = c >> 3;
            x_s[(row * 16 + (sl ^ (row & 7))) * 8 + (c & 7)] = f2b(v);
        }
    }
#pragma unroll
    for (int i = 0; i < 4; ++i) {
        int idx = t + i * 256;
        *(uint4*)&w_s[idx * 8] = *(const uint4*)(W2t + (size_t)idx * 8);
    }
    __syncthreads();
    f32x4 a2[4];
#pragma unroll
    for (int j = 0; j < 4; ++j) a2[j] = (f32x4)0.f;
#pragma unroll
    for (int ks = 0; ks < 4; ++ks) {
        bf16x8 af = *(const bf16x8*)&x_s[(arow * 16 + ((ks * 4 + hi) ^ (arow & 7))) * 8];
#pragma unroll
        for (int j = 0; j < 4; ++j) {
            bf16x8 bf = *(const bf16x8*)&w_s[((ks * 4 + hi) * 64 + 16 * j + lo) * 8];
            a2[j] = __builtin_amdgcn_mfma_f32_16x16x32_bf16(af, bf, a2[j], 0, 0, 0);
        }
    }
#pragma unroll
    for (int j = 0; j < 4; ++j) {
        int c = 16 * j + lo;
        float bv = b2[c];
#pragma unroll
        for (int q = 0; q < 4; ++q) {
            int r = m0 + 16 * w + hi * 4 + q;
            if (r < M) out[(size_t)r * 64 + c] = a2[j][q] + bv;
        }
    }
}

// ---------------------------------------------------------------------------
extern "C" void kernel_launch(void* const* d_in, const int* in_sizes, int n_in,
                              void* d_out, int out_size, void* d_ws, size_t ws_size,
                              hipStream_t stream) {
    const float* x   = (const float*)d_in[0];
    const int*   ei  = (const int*)d_in[1];
    const float* aW  = (const float*)d_in[2];
    const float* ab  = (const float*)d_in[3];
    const float* W1  = (const float*)d_in[4];
    const float* b1  = (const float*)d_in[5];
    const float* W2  = (const float*)d_in[6];
    const float* b2  = (const float*)d_in[7];
    const float* gam = (const float*)d_in[8];
    const float* bet = (const float*)d_in[9];
    const float* Wih = (const float*)d_in[10];
    const float* Whh = (const float*)d_in[11];
    const float* bih = (const float*)d_in[12];
    const float* bhh = (const float*)d_in[13];
    const float* lW1 = (const float*)d_in[14];
    const float* lb1 = (const float*)d_in[15];
    const float* lW2 = (const float*)d_in[16];
    const float* lb2 = (const float*)d_in[17];

    const int N = in_sizes[0] / 128;
    const int E = in_sizes[1] / 2;
    const int L = in_sizes[3] / 2;
    float* out = (float*)d_out;

    char* ws = (char*)d_ws;
    size_t off = 0;
    auto alloc = [&](size_t bytes) -> void* {
        void* p = ws + off;
        off = (off + bytes + 255) & ~(size_t)255;
        return p;
    };
    int* offs = (int*)alloc((size_t)(N + 1) * 4);
    int* cur  = (int*)alloc((size_t)N * 4);
    int* part = (int*)alloc(64 * 4);
    u16* adj  = (u16*)alloc((size_t)2 * E * 2);
    u16* tW1  = (u16*)alloc((size_t)L * 16384 * 2);
    u16* tW2  = (u16*)alloc((size_t)L * 16384 * 2);
    u16* tWih = (u16*)alloc((size_t)49152 * 2);
    u16* tWhh = (u16*)alloc((size_t)49152 * 2);
    u16* tlW1 = (u16*)alloc((size_t)16384 * 2);
    u16* tlW2 = (u16*)alloc((size_t)8192 * 2);
    u16* xb   = (u16*)alloc((size_t)N * 128 * 2);
    u16* comb = (u16*)alloc((size_t)N * 128 * 2);
    float* hF = (float*)alloc((size_t)N * 128 * 4);
    u16* hAb  = (u16*)alloc((size_t)N * 128 * 2);
    u16* hBb  = (u16*)alloc((size_t)N * 128 * 2);
    (void)ws_size; (void)n_in; (void)out_size;

    hipMemsetAsync(cur, 0, (size_t)N * 4, stream);

    int wchunks = L * 4096 + 12288 + 3072;
    k_prep_w<<<(wchunks + 255) / 256, 256, 0, stream>>>(W1, W2, Wih, Whh, lW1, lW2,
                                                        tW1, tW2, tWih, tWhh, tlW1, tlW2, L);
    k_f2b<<<(N * 16 + 255) / 256, 256, 0, stream>>>(x, xb, N * 16);

    k_deg<<<(E + 255) / 256, 256, 0, stream>>>(ei, cur, E);
    int nb = (N + 1023) / 1024;
    k_scan_sum<<<nb, 1024, 0, stream>>>(cur, part, N);
    k_scan_part<<<1, 64, 0, stream>>>(part, nb);
    k_scan_write<<<nb, 1024, 0, stream>>>(cur, part, offs, N);
    hipMemcpyAsync(cur, offs, (size_t)N * 4, hipMemcpyDeviceToDevice, stream);
    k_fill<<<(E + 255) / 256, 256, 0, stream>>>(ei, cur, adj, E);

    const int mb = (N + 127) / 128;
    // layer 0 (h == 0)
    k_agg<<<(N + 3) / 4, 256, 0, stream>>>(xb, adj, offs, aW, ab, comb, N);
    k_layer<true, true><<<mb, 512, 0, stream>>>(
        comb, nullptr, nullptr, tW1, b1, tW2, b2, gam, bet,
        tWih, tWhh, bih, bhh, hF, hAb, N);
    // layer 1
    k_agg<<<(N + 3) / 4, 256, 0, stream>>>(hAb, adj, offs, aW + 512, ab + 2, comb, N);
    k_layer<false, false><<<mb, 512, 0, stream>>>(
        comb, hAb, hF, tW1 + 16384, b1 + 128, tW2 + 16384, b2 + 128,
        gam + 128, bet + 128, tWih, tWhh, bih, bhh, nullptr, hBb, N);

    k_final<<<(N + 63) / 64, 256, 0, stream>>>(hBb, tlW1, lb1, tlW2, lb2, out, N);
}

// Round 4
// 263.535 us; speedup vs baseline: 3.4933x; 1.0793x over previous
//
#include <hip/hip_runtime.h>
#include <math.h>

typedef unsigned short u16;
typedef __attribute__((ext_vector_type(8))) short bf16x8;
typedef __attribute__((ext_vector_type(4))) float f32x4;

__device__ __forceinline__ u16 f2b(float f) {
    union { float f; unsigned u; } v; v.f = f;
    unsigned r = (v.u + 0x7FFF + ((v.u >> 16) & 1)) >> 16;
    return (u16)r;
}
__device__ __forceinline__ float b2f(u16 h) {
    union { unsigned u; float f; } v; v.u = (unsigned)h << 16;
    return v.f;
}
__device__ __forceinline__ float fsig(float x) { return 1.f / (1.f + __expf(-x)); }
__device__ __forceinline__ float ftanh(float x) {
    float e = __expf(2.f * x);
    return 1.f - 2.f / (e + 1.f);
}

__device__ __forceinline__ void gll16(const void* g, void* l) {
    __builtin_amdgcn_global_load_lds(
        (const __attribute__((address_space(1))) void*)g,
        (__attribute__((address_space(3))) void*)l, 16, 0, 0);
}

// stage BYTES (multiple of 8 KB) linearly: wave w writes 1 KB chunks
template <int BYTES>
__device__ __forceinline__ void stage_lin(const u16* g, u16* l, int wid, int lane) {
#pragma unroll
    for (int i = 0; i < BYTES / 8192; ++i) {
        int off = (i * 8 + wid) * 1024;  // bytes
        gll16((const char*)g + off + lane * 16, (char*)l + off);
    }
}

// ---------------- CSR build ----------------
__global__ void k_deg(const int* __restrict__ ei, int* __restrict__ cnt, int E) {
    int e = blockIdx.x * 256 + threadIdx.x;
    if (e < E) {
        atomicAdd(&cnt[ei[e]], 1);
        atomicAdd(&cnt[ei[E + e]], 1);
    }
}

__global__ __launch_bounds__(1024) void k_scan_sum(const int* __restrict__ cnt,
                                                   int* __restrict__ part, int N) {
    __shared__ int sd[16];
    int t = threadIdx.x;
    int i = blockIdx.x * 1024 + t;
    int v = (i < N) ? cnt[i] : 0;
#pragma unroll
    for (int o = 32; o; o >>= 1) v += __shfl_xor(v, o);
    if ((t & 63) == 0) sd[t >> 6] = v;
    __syncthreads();
    if (t < 16) {
        int s = sd[t];
#pragma unroll
        for (int o = 8; o; o >>= 1) s += __shfl_xor(s, o);
        if (t == 0) part[blockIdx.x] = s;
    }
}

__global__ void k_scan_part(int* __restrict__ part, int nb) {
    int t = threadIdx.x;
    int v = (t < nb) ? part[t] : 0;
#pragma unroll
    for (int o = 1; o < 64; o <<= 1) {
        int u = __shfl_up(v, o);
        if ((t & 63) >= o) v += u;
    }
    if (t < nb) part[t] = v;
}

__global__ __launch_bounds__(1024) void k_scan_write(const int* __restrict__ cnt,
                                                     const int* __restrict__ part,
                                                     int* __restrict__ offs, int N) {
    __shared__ int sd[16];
    int t = threadIdx.x, lane = t & 63, wid = t >> 6;
    int i = blockIdx.x * 1024 + t;
    int v = (i < N) ? cnt[i] : 0;
    int inc = v;
#pragma unroll
    for (int o = 1; o < 64; o <<= 1) {
        int u = __shfl_up(inc, o);
        if (lane >= o) inc += u;
    }
    if (lane == 63) sd[wid] = inc;
    __syncthreads();
    if (wid == 0) {
        int wv = (lane < 16) ? sd[lane] : 0;
#pragma unroll
        for (int o = 1; o < 16; o <<= 1) {
            int u = __shfl_up(wv, o);
            if (lane >= o) wv += u;
        }
        if (lane < 16) sd[lane] = wv;
    }
    __syncthreads();
    int base = (blockIdx.x > 0 ? part[blockIdx.x - 1] : 0) + (wid > 0 ? sd[wid - 1] : 0);
    if (i < N) offs[i + 1] = base + inc;
    if (i == 0 && blockIdx.x == 0) offs[0] = 0;
}

__global__ void k_fill(const int* __restrict__ ei, int* __restrict__ cur,
                       u16* __restrict__ adj, int E) {
    int e = blockIdx.x * 256 + threadIdx.x;
    if (e < E) {
        int s = ei[e], d = ei[E + e];
        int p = atomicAdd(&cur[s], 1); adj[p] = (u16)d;
        int q = atomicAdd(&cur[d], 1); adj[q] = (u16)s;
    }
}

// ---------------- weight prep ----------------
// W1/W2/lW1/lW2: [kslot][n][8] chunks.  GRU: gate-triple permuted chunks:
// 8 stages (half*4+kc), each [q 0..3][mat ih/hh][cc 0..191][8]
__device__ __forceinline__ void conv_chunk(const float* __restrict__ src,
                                           u16* __restrict__ dst, int c, int NC) {
    int sl = c / NC, n = c - sl * NC;
    u16 tmp[8];
#pragma unroll
    for (int i = 0; i < 8; ++i) tmp[i] = f2b(src[(size_t)(sl * 8 + i) * NC + n]);
    *(uint4*)(dst + (size_t)c * 8) = *(const uint4*)tmp;
}

__global__ void k_prep_w(const float* __restrict__ W1, const float* __restrict__ W2,
                         const float* __restrict__ Wih, const float* __restrict__ Whh,
                         const float* __restrict__ lW1, const float* __restrict__ lW2,
                         u16* __restrict__ tW1, u16* __restrict__ tW2,
                         u16* __restrict__ tGRU,
                         u16* __restrict__ tlW1, u16* __restrict__ tlW2, int L) {
    int c = blockIdx.x * 256 + threadIdx.x;
    if (c < L * 2048) { int l = c >> 11; conv_chunk(W1 + (size_t)l * 16384, tW1 + (size_t)l * 16384, c & 2047, 128); return; }
    c -= L * 2048;
    if (c < L * 2048) { int l = c >> 11; conv_chunk(W2 + (size_t)l * 16384, tW2 + (size_t)l * 16384, c & 2047, 128); return; }
    c -= L * 2048;
    if (c < 12288) {
        int s = c / 1536, r = c % 1536;
        int q = r / 384, r2 = r % 384;
        int mat = r2 / 192, cc = r2 % 192;
        int h = s >> 2, kc = s & 3;
        int tt = cc >> 4, ii = cc & 15;
        int g = tt >> 2;
        int ocol = g * 128 + h * 64 + (tt & 3) * 16 + ii;
        const float* src = mat ? Whh : Wih;
        int kb = (kc * 4 + q) * 8;
        u16 tmp[8];
#pragma unroll
        for (int e = 0; e < 8; ++e) tmp[e] = f2b(src[(size_t)(kb + e) * 384 + ocol]);
        *(uint4*)(tGRU + (size_t)c * 8) = *(const uint4*)tmp;
        return;
    }
    c -= 12288;
    if (c < 2048) { conv_chunk(lW1, tlW1, c, 128); return; }
    c -= 2048;
    if (c < 1024) { conv_chunk(lW2, tlW2, c, 64); return; }
}

__global__ void k_f2b(const float* __restrict__ src, u16* __restrict__ dst, int n8) {
    int i = blockIdx.x * 256 + threadIdx.x;
    if (i < n8) {
        float4 a = *(const float4*)(src + (size_t)i * 8);
        float4 b = *(const float4*)(src + (size_t)i * 8 + 4);
        u16 t[8] = {f2b(a.x), f2b(a.y), f2b(a.z), f2b(a.w),
                    f2b(b.x), f2b(b.y), f2b(b.z), f2b(b.w)};
        *(uint4*)(dst + (size_t)i * 8) = *(const uint4*)t;
    }
}

// ---------------- aggregation + attention + comb (wave per node) -----------
__global__ __launch_bounds__(256) void k_agg(const u16* __restrict__ xb,
                                             const u16* __restrict__ adj,
                                             const int* __restrict__ offs,
                                             const float* __restrict__ aW,
                                             const float* __restrict__ ab,
                                             u16* __restrict__ comb, int N) {
    int n = blockIdx.x * 4 + (threadIdx.x >> 6);
    if (n >= N) return;
    int l = threadIdx.x & 63;
    int half = l >> 5, e0 = (l & 31) * 4;
    int beg = offs[n], end = offs[n + 1];
    float s0 = 0.f, s1 = 0.f, s2 = 0.f, s3 = 0.f;
    float m0 = -3.402823e38f, m1 = m0, m2 = m0, m3 = m0;
    int j = beg + half;
    for (; j + 6 < end; j += 8) {
        int a0 = adj[j], a1 = adj[j + 2], a2 = adj[j + 4], a3 = adj[j + 6];
        ushort4 v0 = *(const ushort4*)(xb + (size_t)a0 * 128 + e0);
        ushort4 v1 = *(const ushort4*)(xb + (size_t)a1 * 128 + e0);
        ushort4 v2 = *(const ushort4*)(xb + (size_t)a2 * 128 + e0);
        ushort4 v3 = *(const ushort4*)(xb + (size_t)a3 * 128 + e0);
        float f0, f1, f2, f3;
        f0 = b2f(v0.x); f1 = b2f(v0.y); f2 = b2f(v0.z); f3 = b2f(v0.w);
        s0 += f0; s1 += f1; s2 += f2; s3 += f3;
        m0 = fmaxf(m0, f0); m1 = fmaxf(m1, f1); m2 = fmaxf(m2, f2); m3 = fmaxf(m3, f3);
        f0 = b2f(v1.x); f1 = b2f(v1.y); f2 = b2f(v1.z); f3 = b2f(v1.w);
        s0 += f0; s1 += f1; s2 += f2; s3 += f3;
        m0 = fmaxf(m0, f0); m1 = fmaxf(m1, f1); m2 = fmaxf(m2, f2); m3 = fmaxf(m3, f3);
        f0 = b2f(v2.x); f1 = b2f(v2.y); f2 = b2f(v2.z); f3 = b2f(v2.w);
        s0 += f0; s1 += f1; s2 += f2; s3 += f3;
        m0 = fmaxf(m0, f0); m1 = fmaxf(m1, f1); m2 = fmaxf(m2, f2); m3 = fmaxf(m3, f3);
        f0 = b2f(v3.x); f1 = b2f(v3.y); f2 = b2f(v3.z); f3 = b2f(v3.w);
        s0 += f0; s1 += f1; s2 += f2; s3 += f3;
        m0 = fmaxf(m0, f0); m1 = fmaxf(m1, f1); m2 = fmaxf(m2, f2); m3 = fmaxf(m3, f3);
    }
    for (; j < end; j += 2) {
        int nb = adj[j];
        ushort4 v = *(const ushort4*)(xb + (size_t)nb * 128 + e0);
        float f0 = b2f(v.x), f1 = b2f(v.y), f2 = b2f(v.z), f3 = b2f(v.w);
        s0 += f0; s1 += f1; s2 += f2; s3 += f3;
        m0 = fmaxf(m0, f0); m1 = fmaxf(m1, f1); m2 = fmaxf(m2, f2); m3 = fmaxf(m3, f3);
    }
    s0 += __shfl_xor(s0, 32); m0 = fmaxf(m0, __shfl_xor(m0, 32));
    s1 += __shfl_xor(s1, 32); m1 = fmaxf(m1, __shfl_xor(m1, 32));
    s2 += __shfl_xor(s2, 32); m2 = fmaxf(m2, __shfl_xor(m2, 32));
    s3 += __shfl_xor(s3, 32); m3 = fmaxf(m3, __shfl_xor(m3, 32));
    if (beg == end) { m0 = m1 = m2 = m3 = 0.f; }
    float p0 = 0.f, p1 = 0.f;
    {
        float2 w0v = *(const float2*)(aW + (size_t)e0 * 2);
        float2 w1v = *(const float2*)(aW + (size_t)(e0 + 1) * 2);
        float2 w2v = *(const float2*)(aW + (size_t)(e0 + 2) * 2);
        float2 w3v = *(const float2*)(aW + (size_t)(e0 + 3) * 2);
        float2 u0v = *(const float2*)(aW + (size_t)(128 + e0) * 2);
        float2 u1v = *(const float2*)(aW + (size_t)(128 + e0 + 1) * 2);
        float2 u2v = *(const float2*)(aW + (size_t)(128 + e0 + 2) * 2);
        float2 u3v = *(const float2*)(aW + (size_t)(128 + e0 + 3) * 2);
        p0 = s0 * w0v.x + s1 * w1v.x + s2 * w2v.x + s3 * w3v.x
           + m0 * u0v.x + m1 * u1v.x + m2 * u2v.x + m3 * u3v.x;
        p1 = s0 * w0v.y + s1 * w1v.y + s2 * w2v.y + s3 * w3v.y
           + m0 * u0v.y + m1 * u1v.y + m2 * u2v.y + m3 * u3v.y;
    }
#pragma unroll
    for (int o = 16; o; o >>= 1) { p0 += __shfl_xor(p0, o); p1 += __shfl_xor(p1, o); }
    p0 += ab[0]; p1 += ab[1];
    float pm = fmaxf(p0, p1);
    float ea = __expf(p0 - pm), eb = __expf(p1 - pm);
    float w0 = ea / (ea + eb), w1 = 1.f - w0;
    if (half == 0) {
        ushort4 xv = *(const ushort4*)(xb + (size_t)n * 128 + e0);
        ushort4 o;
        o.x = f2b(b2f(xv.x) + w0 * s0 + w1 * m0);
        o.y = f2b(b2f(xv.y) + w0 * s1 + w1 * m1);
        o.z = f2b(b2f(xv.z) + w0 * s2 + w1 * m2);
        o.w = f2b(b2f(xv.w) + w0 * s3 + w1 * m3);
        *(ushort4*)(comb + (size_t)n * 128 + e0) = o;
    }
}

// ---------------- fused layer: MLP1 -> MLP2+BN -> GRU (80 KB LDS, 2/CU) ----
template <bool H0, bool WF32>
__global__ __launch_bounds__(512, 4) void k_layer(
    const u16* __restrict__ Cb, const u16* __restrict__ Hb,
    const float* __restrict__ Hf,
    const u16* __restrict__ W1t, const float* __restrict__ b1,
    const u16* __restrict__ W2t, const float* __restrict__ b2,
    const float* __restrict__ gam, const float* __restrict__ bet,
    const u16* __restrict__ tG,
    const float* __restrict__ bih, const float* __restrict__ bhh,
    float* __restrict__ HnF, u16* __restrict__ HnB, int M) {
    __shared__ __align__(16) u16 x_s[128 * 16 * 8];   // 32 KB: comb -> z1 -> z
    __shared__ __align__(16) u16 b_s[2][12288];       // 2 x 24 KB weight dbuf
    const int t = threadIdx.x;
    const int m0 = blockIdx.x * 128;
    const int wid = t >> 6, lane = t & 63, lo = lane & 15, hi = lane >> 4;
    const int w = wid;
    const int arow = 16 * w + lo;

    // ---- prologue: x_s (swizzled src), h->regs, W1 chunks
#pragma unroll
    for (int i = 0; i < 4; ++i) {
        int off = (i * 8 + wid) * 1024;              // bytes into x_s
        int row = (off >> 8) + (lane >> 4);          // 256 B per row
        int s = lane & 15;
        int gr = m0 + row; gr = gr < M ? gr : M - 1;
        gll16(Cb + (size_t)gr * 128 + ((s ^ (row & 7)) * 8), (char*)x_s + off);
    }
    bf16x8 hreg[4];
    if (!H0) {
        int gr = m0 + arow; gr = gr < M ? gr : M - 1;
#pragma unroll
        for (int kc = 0; kc < 4; ++kc)
            hreg[kc] = *(const bf16x8*)(Hb + (size_t)gr * 128 + (kc * 4 + hi) * 8);
    }
    stage_lin<16384>(W1t, b_s[0], wid, lane);
    stage_lin<16384>(W1t + 8192, b_s[1], wid, lane);
    __syncthreads();

    // ---- GEMM1: z1 = relu(comb @ W1 + b1)
    f32x4 acc[8];
#pragma unroll
    for (int j = 0; j < 8; ++j) acc[j] = (f32x4)0.f;
#pragma unroll
    for (int ks = 0; ks < 4; ++ks) {
        bf16x8 af = *(const bf16x8*)&x_s[(arow * 16 + ((ks * 4 + hi) ^ (arow & 7))) * 8];
        const u16* wb = b_s[ks >> 1];
        int loc = (ks & 1) * 4 + hi;
#pragma unroll
        for (int j = 0; j < 8; ++j) {
            bf16x8 bf = *(const bf16x8*)&wb[((size_t)loc * 128 + 16 * j + lo) * 8];
            acc[j] = __builtin_amdgcn_mfma_f32_16x16x32_bf16(af, bf, acc[j], 0, 0, 0);
        }
    }
    __syncthreads();                                  // all b/x reads done
    stage_lin<16384>(W2t, b_s[0], wid, lane);
    stage_lin<16384>(W2t + 8192, b_s[1], wid, lane);
#pragma unroll
    for (int j = 0; j < 8; ++j) {
        int c = 16 * j + lo;
        float bv = b1[c];
#pragma unroll
        for (int q = 0; q < 4; ++q) {
            int row = 16 * w + hi * 4 + q;
            float v = fmaxf(acc[j][q] + bv, 0.f);
            int sl = c >> 3;
            x_s[(row * 16 + (sl ^ (row & 7))) * 8 + (c & 7)] = f2b(v);
        }
    }
    __syncthreads();

    // ---- GEMM2: z = (z1 @ W2 + b2) * gam + bet
#pragma unroll
    for (int j = 0; j < 8; ++j) acc[j] = (f32x4)0.f;
#pragma unroll
    for (int ks = 0; ks < 4; ++ks) {
        bf16x8 af = *(const bf16x8*)&x_s[(arow * 16 + ((ks * 4 + hi) ^ (arow & 7))) * 8];
        const u16* wb = b_s[ks >> 1];
        int loc = (ks & 1) * 4 + hi;
#pragma unroll
        for (int j = 0; j < 8; ++j) {
            bf16x8 bf = *(const bf16x8*)&wb[((size_t)loc * 128 + 16 * j + lo) * 8];
            acc[j] = __builtin_amdgcn_mfma_f32_16x16x32_bf16(af, bf, acc[j], 0, 0, 0);
        }
    }
    __syncthreads();
    stage_lin<24576>(tG, b_s[0], wid, lane);           // GRU stage 0 (h0,kc0)
    stage_lin<24576>(tG + 12288, b_s[1], wid, lane);   // stage 1 (h0,kc1)
#pragma unroll
    for (int j = 0; j < 8; ++j) {
        int c = 16 * j + lo;
        float bv = b2[c], gv = gam[c], tv = bet[c];
#pragma unroll
        for (int q = 0; q < 4; ++q) {
            int row = 16 * w + hi * 4 + q;
            float v = (acc[j][q] + bv) * gv + tv;
            int sl = c >> 3;
            x_s[(row * 16 + (sl ^ (row & 7))) * 8 + (c & 7)] = f2b(v);
        }
    }
    __syncthreads();

    // ---- GRU, two column-halves of 192 permuted gate cols
    f32x4 racc[4], uacc[4], nza[4], nha[4];

    auto gru_kc = [&](const u16* buf, int kc) {
        bf16x8 zf = *(const bf16x8*)&x_s[(arow * 16 + ((kc * 4 + hi) ^ (arow & 7))) * 8];
#pragma unroll
        for (int jj = 0; jj < 4; ++jj) {
            const u16* bi = &buf[((size_t)(hi * 2 + 0) * 192) * 8];
            bf16x8 wr = *(const bf16x8*)&bi[(jj * 16 + lo) * 8];
            racc[jj] = __builtin_amdgcn_mfma_f32_16x16x32_bf16(zf, wr, racc[jj], 0, 0, 0);
            bf16x8 wu = *(const bf16x8*)&bi[(64 + jj * 16 + lo) * 8];
            uacc[jj] = __builtin_amdgcn_mfma_f32_16x16x32_bf16(zf, wu, uacc[jj], 0, 0, 0);
            bf16x8 wn = *(const bf16x8*)&bi[(128 + jj * 16 + lo) * 8];
            nza[jj] = __builtin_amdgcn_mfma_f32_16x16x32_bf16(zf, wn, nza[jj], 0, 0, 0);
            if (!H0) {
                const u16* bh = &buf[((size_t)(hi * 2 + 1) * 192) * 8];
                bf16x8 vr = *(const bf16x8*)&bh[(jj * 16 + lo) * 8];
                racc[jj] = __builtin_amdgcn_mfma_f32_16x16x32_bf16(hreg[kc], vr, racc[jj], 0, 0, 0);
                bf16x8 vu = *(const bf16x8*)&bh[(64 + jj * 16 + lo) * 8];
                uacc[jj] = __builtin_amdgcn_mfma_f32_16x16x32_bf16(hreg[kc], vu, uacc[jj], 0, 0, 0);
                bf16x8 vn = *(const bf16x8*)&bh[(128 + jj * 16 + lo) * 8];
                nha[jj] = __builtin_amdgcn_mfma_f32_16x16x32_bf16(hreg[kc], vn, nha[jj], 0, 0, 0);
            }
        }
    };

    auto gru_epi = [&](int h) {
#pragma unroll
        for (int ct = 0; ct < 4; ++ct) {
            int c = h * 64 + ct * 16 + lo;
            float b_r = bih[c] + bhh[c];
            float b_u = bih[c + 128] + bhh[c + 128];
            float b_in = bih[c + 256], b_hn = bhh[c + 256];
#pragma unroll
            for (int q = 0; q < 4; ++q) {
                int r = m0 + 16 * w + hi * 4 + q;
                if (r < M) {
                    float rr = fsig(racc[ct][q] + b_r);
                    float uu = fsig(uacc[ct][q] + b_u);
                    float hterm = H0 ? b_hn : (nha[ct][q] + b_hn);
                    float nn = ftanh(nza[ct][q] + b_in + rr * hterm);
                    float hv = H0 ? 0.f : Hf[(size_t)r * 128 + c];
                    float o = (1.f - uu) * nn + uu * hv;
                    if (WF32) HnF[(size_t)r * 128 + c] = o;
                    HnB[(size_t)r * 128 + c] = f2b(o);
                }
            }
        }
    };

    // half 0
#pragma unroll
    for (int j = 0; j < 4; ++j) { racc[j] = (f32x4)0.f; uacc[j] = (f32x4)0.f;
                                  nza[j] = (f32x4)0.f; nha[j] = (f32x4)0.f; }
    gru_kc(b_s[0], 0);
    gru_kc(b_s[1], 1);
    __syncthreads();
    stage_lin<24576>(tG + 2 * 12288, b_s[0], wid, lane);
    stage_lin<24576>(tG + 3 * 12288, b_s[1], wid, lane);
    __syncthreads();
    gru_kc(b_s[0], 2);
    gru_kc(b_s[1], 3);
    __syncthreads();
    stage_lin<24576>(tG + 4 * 12288, b_s[0], wid, lane);
    stage_lin<24576>(tG + 5 * 12288, b_s[1], wid, lane);
    gru_epi(0);                                       // hides stage latency
    __syncthreads();

    // half 1
#pragma unroll
    for (int j = 0; j < 4; ++j) { racc[j] = (f32x4)0.f; uacc[j] = (f32x4)0.f;
                                  nza[j] = (f32x4)0.f; nha[j] = (f32x4)0.f; }
    gru_kc(b_s[0], 0);
    gru_kc(b_s[1], 1);
    __syncthreads();
    stage_lin<24576>(tG + 6 * 12288, b_s[0], wid, lane);
    stage_lin<24576>(tG + 7 * 12288, b_s[1], wid, lane);
    __syncthreads();
    gru_kc(b_s[0], 2);
    gru_kc(b_s[1], 3);
    gru_epi(1);
}

// ---------------- fused final MLP: out = relu(h@lW1+lb1)@lW2 + lb2 --------
__global__ __launch_bounds__(256, 2) void k_final(const u16* __restrict__ Hb,
                                                  const u16* __restrict__ W1t,
                                                  const float* __restrict__ b1,
                                                  const u16* __restrict__ W2t,
                                                  const float* __restrict__ b2,
                                                  float* __restrict__ out, int M) {
    __shared__ __align__(16) u16 x_s[64 * 16 * 8];
    __shared__ __align__(16) u16 w_s[16 * 128 * 8];
    const int t = threadIdx.x;
    const int m0 = blockIdx.x * 64;
    const int w = t >> 6, l = t & 63, lo = l & 15, hi = l >> 4;
    const int arow = 16 * w + lo;
#pragma unroll
    for (int i = 0; i < 4; ++i) {
        int idx = t + i * 256;
        int row = idx >> 4, sl = idx & 15;
        int gr = m0 + row; gr = gr < M ? gr : M - 1;
        *(uint4*)&x_s[(row * 16 + (sl ^ (row & 7))) * 8] =
            *(const uint4*)(Hb + (size_t)gr * 128 + sl * 8);
    }
#pragma unroll
    for (int i = 0; i < 8; ++i) {
        int idx = t + i * 256;
        *(uint4*)&w_s[idx * 8] = *(const uint4*)(W1t + (size_t)idx * 8);
    }
    __syncthreads();
    f32x4 acc[8];
#pragma unroll
    for (int j = 0; j < 8; ++j) acc[j] = (f32x4)0.f;
#pragma unroll
    for (int ks = 0; ks < 4; ++ks) {
        bf16x8 af = *(const bf16x8*)&x_s[(arow * 16 + ((ks * 4 + hi) ^ (arow & 7))) * 8];
#pragma unroll
        for (int j = 0; j < 8; ++j) {
            bf16x8 bf = *(const bf16x8*)&w_s[((ks * 4 + hi) * 128 + 16 * j + lo) * 8];
            acc[j] = __builtin_amdgcn_mfma_f32_16x16x32_bf16(af, bf, acc[j], 0, 0, 0);
        }
    }
    __syncthreads();
#pragma unroll
    for (int j = 0; j < 8; ++j) {
        int c = 16 * j + lo;
        float bv = b1[c];
#pragma unroll
        for (int q = 0; q < 4; ++q) {
            int row = 16 * w + hi * 4 + q;
            float v = fmaxf(acc[j][q] + bv, 0.f);
            int sl = c >> 3;
            x_s[(row * 16 + (sl ^ (row & 7))) * 8 + (c & 7)] = f2b(v);
        }
    }
#pragma unroll
    for (int i = 0; i < 4; ++i) {
        int idx = t + i * 256;
        *(uint4*)&w_s[idx * 8] = *(const uint4*)(W2t + (size_t)idx * 8);
    }
    __syncthreads();
    f32x4 a2[4];
#pragma unroll
    for (int j = 0; j < 4; ++j) a2[j] = (f32x4)0.f;
#pragma unroll
    for (int ks = 0; ks < 4; ++ks) {
        bf16x8 af = *(const bf16x8*)&x_s[(arow * 16 + ((ks * 4 + hi) ^ (arow & 7))) * 8];
#pragma unroll
        for (int j = 0; j < 4; ++j) {
            bf16x8 bf = *(const bf16x8*)&w_s[((ks * 4 + hi) * 64 + 16 * j + lo) * 8];
            a2[j] = __builtin_amdgcn_mfma_f32_16x16x32_bf16(af, bf, a2[j], 0, 0, 0);
        }
    }
#pragma unroll
    for (int j = 0; j < 4; ++j) {
        int c = 16 * j + lo;
        float bv = b2[c];
#pragma unroll
        for (int q = 0; q < 4; ++q) {
            int r = m0 + 16 * w + hi * 4 + q;
            if (r < M) out[(size_t)r * 64 + c] = a2[j][q] + bv;
        }
    }
}

// ---------------------------------------------------------------------------
extern "C" void kernel_launch(void* const* d_in, const int* in_sizes, int n_in,
                              void* d_out, int out_size, void* d_ws, size_t ws_size,
                              hipStream_t stream) {
    const float* x   = (const float*)d_in[0];
    const int*   ei  = (const int*)d_in[1];
    const float* aW  = (const float*)d_in[2];
    const float* ab  = (const float*)d_in[3];
    const float* W1  = (const float*)d_in[4];
    const float* b1  = (const float*)d_in[5];
    const float* W2  = (const float*)d_in[6];
    const float* b2  = (const float*)d_in[7];
    const float* gam = (const float*)d_in[8];
    const float* bet = (const float*)d_in[9];
    const float* Wih = (const float*)d_in[10];
    const float* Whh = (const float*)d_in[11];
    const float* bih = (const float*)d_in[12];
    const float* bhh = (const float*)d_in[13];
    const float* lW1 = (const float*)d_in[14];
    const float* lb1 = (const float*)d_in[15];
    const float* lW2 = (const float*)d_in[16];
    const float* lb2 = (const float*)d_in[17];

    const int N = in_sizes[0] / 128;
    const int E = in_sizes[1] / 2;
    const int L = in_sizes[3] / 2;
    float* out = (float*)d_out;

    char* ws = (char*)d_ws;
    size_t off = 0;
    auto alloc = [&](size_t bytes) -> void* {
        void* p = ws + off;
        off = (off + bytes + 255) & ~(size_t)255;
        return p;
    };
    int* offs = (int*)alloc((size_t)(N + 1) * 4);
    int* cur  = (int*)alloc((size_t)N * 4);
    int* part = (int*)alloc(64 * 4);
    u16* adj  = (u16*)alloc((size_t)2 * E * 2);
    u16* tW1  = (u16*)alloc((size_t)L * 16384 * 2);
    u16* tW2  = (u16*)alloc((size_t)L * 16384 * 2);
    u16* tGRU = (u16*)alloc((size_t)98304 * 2);
    u16* tlW1 = (u16*)alloc((size_t)16384 * 2);
    u16* tlW2 = (u16*)alloc((size_t)8192 * 2);
    u16* xb   = (u16*)alloc((size_t)N * 128 * 2);
    u16* comb = (u16*)alloc((size_t)N * 128 * 2);
    float* hF = (float*)alloc((size_t)N * 128 * 4);
    u16* hAb  = (u16*)alloc((size_t)N * 128 * 2);
    u16* hBb  = (u16*)alloc((size_t)N * 128 * 2);
    (void)ws_size; (void)n_in; (void)out_size;

    hipMemsetAsync(cur, 0, (size_t)N * 4, stream);

    int wchunks = L * 4096 + 12288 + 3072;
    k_prep_w<<<(wchunks + 255) / 256, 256, 0, stream>>>(W1, W2, Wih, Whh, lW1, lW2,
                                                        tW1, tW2, tGRU, tlW1, tlW2, L);
    k_f2b<<<(N * 16 + 255) / 256, 256, 0, stream>>>(x, xb, N * 16);

    k_deg<<<(E + 255) / 256, 256, 0, stream>>>(ei, cur, E);
    int nb = (N + 1023) / 1024;
    k_scan_sum<<<nb, 1024, 0, stream>>>(cur, part, N);
    k_scan_part<<<1, 64, 0, stream>>>(part, nb);
    k_scan_write<<<nb, 1024, 0, stream>>>(cur, part, offs, N);
    hipMemcpyAsync(cur, offs, (size_t)N * 4, hipMemcpyDeviceToDevice, stream);
    k_fill<<<(E + 255) / 256, 256, 0, stream>>>(ei, cur, adj, E);

    const int mb = (N + 127) / 128;
    // layer 0 (h == 0)
    k_agg<<<(N + 3) / 4, 256, 0, stream>>>(xb, adj, offs, aW, ab, comb, N);
    k_layer<true, true><<<mb, 512, 0, stream>>>(
        comb, nullptr, nullptr, tW1, b1, tW2, b2, gam, bet,
        tGRU, bih, bhh, hF, hAb, N);
    // layer 1
    k_agg<<<(N + 3) / 4, 256, 0, stream>>>(hAb, adj, offs, aW + 512, ab + 2, comb, N);
    k_layer<false, false><<<mb, 512, 0, stream>>>(
        comb, hAb, hF, tW1 + 16384, b1 + 128, tW2 + 16384, b2 + 128,
        gam + 128, bet + 128, tGRU, bih, bhh, nullptr, hBb, N);

    k_final<<<(N + 63) / 64, 256, 0, stream>>>(hBb, tlW1, lb1, tlW2, lb2, out, N);
}